// Round 4
// baseline (263.007 us; speedup 1.0000x reference)
//
#include <hip/hip_runtime.h>
#include <math.h>

#define E_DIM 1024
#define H_DIM 64
#define S_LEN 4096
#define B_SZ  4

typedef short s16x8 __attribute__((ext_vector_type(8)));
typedef short s16x4 __attribute__((ext_vector_type(4)));
typedef float f32x4 __attribute__((ext_vector_type(4)));
typedef unsigned short u16;
typedef unsigned int u32;

// q is pre-scaled by 1/sqrt(H) * log2(e) so attention uses exp2 throughout.
#define QSCALE 0.180336880f

static __device__ __forceinline__ u16 f2b(float f) {
    u32 u = __builtin_bit_cast(u32, f);
    u += 0x7fffu + ((u >> 16) & 1u);        // RNE
    return (u16)(u >> 16);
}
static __device__ __forceinline__ u32 pk2(float lo, float hi) {
    return (u32)f2b(lo) | ((u32)f2b(hi) << 16);
}

#if defined(__has_builtin)
#  if __has_builtin(__builtin_amdgcn_mfma_f32_16x16x16bf16_1k)
#    define USE_1K 1
#  else
#    define USE_1K 0
#  endif
#else
#  define USE_1K 0
#endif

// ---------------------------------------------------------------------------
// Kernel 0: W transpose + bf16 convert.  Wt[mat*64+h][k] = bf16(W_mat[k][h])
// ---------------------------------------------------------------------------
__global__ __launch_bounds__(256) void wt_kernel(
    const float* __restrict__ Wq, const float* __restrict__ Wk,
    const float* __restrict__ Wv, u16* __restrict__ wt)
{
    const int flat = blockIdx.x * 256 + threadIdx.x;   // 0..196607
    const int mat = flat >> 16;
    const int within = flat & 65535;                   // = k*64 + h
    const int kk = within >> 6;
    const int h  = within & 63;
    const float* W = (mat == 0) ? Wq : (mat == 1) ? Wk : Wv;
    wt[(long)(mat * 64 + h) * E_DIM + kk] = f2b(W[within]);
}

// ---------------------------------------------------------------------------
// Kernel 1: QKV projection via MFMA, E-split across 4 waves + LDS reduce.
// Block = 256 threads = 4 waves; wave w covers E-chunk [w*256, w*256+256).
// q stored row-major bf16 PRE-SCALED by QSCALE; k row-major; v transposed
// Vt[b][h][s] bf16.
// ---------------------------------------------------------------------------
__global__ __launch_bounds__(256) void proj_kernel(
    const float* __restrict__ x, const u16* __restrict__ wt,
    const float* __restrict__ bq, const float* __restrict__ bk,
    const float* __restrict__ bv,
    u16* __restrict__ qs, u16* __restrict__ ks, u16* __restrict__ vt)
{
    __shared__ f32x4 red[4][12][64];

    const int tid = threadIdx.x;
    const int w    = tid >> 6;
    const int lane = tid & 63;
    const int l15 = lane & 15, g = lane >> 4;
    const long row0 = (long)blockIdx.x * 16;
    const float* xr = x + (row0 + l15) * E_DIM + w * 256;

    f32x4 z = {0.f, 0.f, 0.f, 0.f};
    f32x4 o[12];
#pragma unroll
    for (int i = 0; i < 12; ++i) o[i] = z;

#pragma unroll
    for (int ke = 0; ke < 256; ke += 32) {
        const float4 fa = *(const float4*)(xr + ke + g * 8);
        const float4 fb = *(const float4*)(xr + ke + g * 8 + 4);
        s16x8 xa;
        xa[0] = (short)f2b(fa.x); xa[1] = (short)f2b(fa.y);
        xa[2] = (short)f2b(fa.z); xa[3] = (short)f2b(fa.w);
        xa[4] = (short)f2b(fb.x); xa[5] = (short)f2b(fb.y);
        xa[6] = (short)f2b(fb.z); xa[7] = (short)f2b(fb.w);
#pragma unroll
        for (int mh = 0; mh < 12; ++mh) {
            const s16x8 wa = *(const s16x8*)(
                wt + (long)(mh * 16 + l15) * E_DIM + w * 256 + ke + g * 8);
            o[mh] = __builtin_amdgcn_mfma_f32_16x16x32_bf16(wa, xa, o[mh], 0, 0, 0);
        }
    }

#pragma unroll
    for (int mh = 0; mh < 12; ++mh) red[w][mh][lane] = o[mh];
    __syncthreads();

    const long rg = row0 + l15;
    const int batch = (int)(rg >> 12);
    const int sl = (int)(rg & 4095);

#pragma unroll
    for (int i = 0; i < 3; ++i) {
        const int mh = w * 3 + i;
        const int mat = mh >> 2, hb = mh & 3;
        f32x4 s = red[0][mh][lane];
        s += red[1][mh][lane];
        s += red[2][mh][lane];
        s += red[3][mh][lane];
        const float* bias = (mat == 0) ? bq : (mat == 1) ? bk : bv;
        const float4 bb = *(const float4*)(bias + hb * 16 + 4 * g);
        float r0 = s[0] + bb.x, r1 = s[1] + bb.y;
        float r2 = s[2] + bb.z, r3 = s[3] + bb.w;
        if (mat == 0) {
            r0 *= QSCALE; r1 *= QSCALE; r2 *= QSCALE; r3 *= QSCALE;
            uint2 pk; pk.x = pk2(r0, r1); pk.y = pk2(r2, r3);
            *(uint2*)(qs + rg * H_DIM + hb * 16 + 4 * g) = pk;
        } else if (mat == 1) {
            uint2 pk; pk.x = pk2(r0, r1); pk.y = pk2(r2, r3);
            *(uint2*)(ks + rg * H_DIM + hb * 16 + 4 * g) = pk;
        } else {
            const long hbase = (long)batch * H_DIM + hb * 16 + 4 * g;
            vt[(hbase + 0) * S_LEN + sl] = f2b(r0);
            vt[(hbase + 1) * S_LEN + sl] = f2b(r1);
            vt[(hbase + 2) * S_LEN + sl] = f2b(r2);
            vt[(hbase + 3) * S_LEN + sl] = f2b(r3);
        }
    }
}

// ---------------------------------------------------------------------------
// Kernel 2: split-K causal flash attention. Wave = (batch, q-tile, chunk).
// Zero LDS, zero barriers, zero dynamic-lane shuffles.
// QK^T transposed (mfma(K,Q)): D col = q = l15, row = key = 4g+r.
// PV computed as O^T = V^T . P^T  (V-frag is A, P is B) so D col = q = l15:
// softmax rescale and 1/l are own-lane ops.
// ---------------------------------------------------------------------------
#if USE_1K
typedef s16x4 vfrag;
#define NVB 8
#else
typedef s16x8 vfrag;
#define NVB 4
#endif

#define LOAD_K(KA, kv0_) do { \
    KA[0] = *(const s16x8*)(kb + (long)((kv0_) + l15) * H_DIM + g * 8); \
    KA[1] = *(const s16x8*)(kb + (long)((kv0_) + l15) * H_DIM + 32 + g * 8); \
    KA[2] = *(const s16x8*)(kb + (long)((kv0_) + 16 + l15) * H_DIM + g * 8); \
    KA[3] = *(const s16x8*)(kb + (long)((kv0_) + 16 + l15) * H_DIM + 32 + g * 8); \
} while (0)

#if USE_1K
// va[2c] = keys kv0+4g+j, va[2c+1] = keys kv0+16+4g+j of h-block c
#define LOAD_V(VA, kv0_) do { \
    _Pragma("unroll") \
    for (int c = 0; c < 4; ++c) { \
        VA[2*c]   = *(const s16x4*)(vtb + (long)(c * 16 + l15) * S_LEN + (kv0_) + 4 * g); \
        VA[2*c+1] = *(const s16x4*)(vtb + (long)(c * 16 + l15) * S_LEN + (kv0_) + 16 + 4 * g); \
    } \
} while (0)
#define PV(VA) do { \
    s16x4 pa0, pa1; \
    pa0[0] = (short)f2b(p[0]); pa0[1] = (short)f2b(p[1]); \
    pa0[2] = (short)f2b(p[2]); pa0[3] = (short)f2b(p[3]); \
    pa1[0] = (short)f2b(p[4]); pa1[1] = (short)f2b(p[5]); \
    pa1[2] = (short)f2b(p[6]); pa1[3] = (short)f2b(p[7]); \
    _Pragma("unroll") \
    for (int c = 0; c < 4; ++c) { \
        o[c] = __builtin_amdgcn_mfma_f32_16x16x16bf16_1k(VA[2*c],   pa0, o[c], 0, 0, 0); \
        o[c] = __builtin_amdgcn_mfma_f32_16x16x16bf16_1k(VA[2*c+1], pa1, o[c], 0, 0, 0); \
    } \
} while (0)
#else
#define LOAD_V(VA, kv0_) do { \
    _Pragma("unroll") \
    for (int c = 0; c < 4; ++c) \
        VA[c] = *(const s16x8*)(vtb + (long)(c * 16 + l15) * S_LEN + (kv0_) + 8 * g); \
} while (0)
// Build P^T B-frag (k = g*8+j, n = q = l15) via quad-exchange, then
// O^T += V^T-frag (A, k = g*8+j) . P^T.
#define PV(VA) do { \
    const u32 w0 = pk2(p[0], p[1]), w1 = pk2(p[2], p[3]); \
    const u32 w2 = pk2(p[4], p[5]), w3 = pk2(p[6], p[7]); \
    const int srcA = ((g & 1) * 2) * 16 + l15, srcB = srcA + 16; \
    const u32 a0 = (u32)__shfl((int)w0, srcA, 64), a1 = (u32)__shfl((int)w1, srcA, 64); \
    const u32 a2 = (u32)__shfl((int)w2, srcA, 64), a3 = (u32)__shfl((int)w3, srcA, 64); \
    const u32 b0 = (u32)__shfl((int)w0, srcB, 64), b1 = (u32)__shfl((int)w1, srcB, 64); \
    const u32 b2 = (u32)__shfl((int)w2, srcB, 64), b3 = (u32)__shfl((int)w3, srcB, 64); \
    const bool losel = (g < 2); \
    const u32 d0 = losel ? a0 : a2, d1 = losel ? a1 : a3; \
    const u32 d2 = losel ? b0 : b2, d3 = losel ? b1 : b3; \
    s16x8 pa; \
    pa[0] = (short)(d0 & 0xffff); pa[1] = (short)(d0 >> 16); \
    pa[2] = (short)(d1 & 0xffff); pa[3] = (short)(d1 >> 16); \
    pa[4] = (short)(d2 & 0xffff); pa[5] = (short)(d2 >> 16); \
    pa[6] = (short)(d3 & 0xffff); pa[7] = (short)(d3 >> 16); \
    _Pragma("unroll") \
    for (int c = 0; c < 4; ++c) \
        o[c] = __builtin_amdgcn_mfma_f32_16x16x32_bf16(VA[c], pa, o[c], 0, 0, 0); \
} while (0)
#endif

#define TILE(KA, VA, kv0arg) do { \
    const int kv0 = (kv0arg); \
    f32x4 z = {0.f, 0.f, 0.f, 0.f}; \
    f32x4 st0 = __builtin_amdgcn_mfma_f32_16x16x32_bf16(KA[0], qa0, z, 0, 0, 0); \
    st0 = __builtin_amdgcn_mfma_f32_16x16x32_bf16(KA[1], qa1, st0, 0, 0, 0); \
    f32x4 st1 = __builtin_amdgcn_mfma_f32_16x16x32_bf16(KA[2], qa0, z, 0, 0, 0); \
    st1 = __builtin_amdgcn_mfma_f32_16x16x32_bf16(KA[3], qa1, st1, 0, 0, 0); \
    float p[8]; \
    if (kv0 + 31 > qw) { \
        _Pragma("unroll") \
        for (int r = 0; r < 4; ++r) { \
            p[r]     = (kv0 + 4 * g + r      <= qg) ? st0[r] : -INFINITY; \
            p[4 + r] = (kv0 + 16 + 4 * g + r <= qg) ? st1[r] : -INFINITY; \
        } \
    } else { \
        _Pragma("unroll") \
        for (int r = 0; r < 4; ++r) { p[r] = st0[r]; p[4 + r] = st1[r]; } \
    } \
    float pm = p[0]; \
    _Pragma("unroll") \
    for (int i = 1; i < 8; ++i) pm = fmaxf(pm, p[i]); \
    pm = fmaxf(pm, __shfl_xor(pm, 16, 64)); \
    pm = fmaxf(pm, __shfl_xor(pm, 32, 64)); \
    const float mnew = fmaxf(m, pm); \
    const float corr = exp2f(m - mnew); \
    float psum = 0.f; \
    _Pragma("unroll") \
    for (int i = 0; i < 8; ++i) { p[i] = exp2f(p[i] - mnew); psum += p[i]; } \
    psum += __shfl_xor(psum, 16, 64); \
    psum += __shfl_xor(psum, 32, 64); \
    lacc = lacc * corr + psum; \
    m = mnew; \
    _Pragma("unroll") \
    for (int c = 0; c < 4; ++c) { \
        o[c][0] *= corr; o[c][1] *= corr; o[c][2] *= corr; o[c][3] *= corr; \
    } \
    PV(VA); \
} while (0)

__global__ __launch_bounds__(64, 4) void attn_kernel(
    const u16* __restrict__ q, const u16* __restrict__ k,
    const u16* __restrict__ vt, float* __restrict__ out,
    float* __restrict__ partO, float* __restrict__ stats2,
    int CHUNK, int direct)
{
    const int lane = threadIdx.x;
    const int l15 = lane & 15, g = lane >> 4;
    const int chunk = blockIdx.x;
    const int qt    = blockIdx.y;
    const int batch = blockIdx.z;
    const int qw = qt * 16;
    const int nc = qw / CHUNK + 1;
    if (chunk >= nc) return;
    const int qg = qw + l15;

    const long base = (long)batch * S_LEN * H_DIM;
    const u16* kb  = k + base;
    const u16* vtb = vt + (long)batch * H_DIM * S_LEN;

    const u16* qrow = q + base + (long)(qw + l15) * H_DIM;
    const s16x8 qa0 = *(const s16x8*)(qrow + g * 8);
    const s16x8 qa1 = *(const s16x8*)(qrow + 32 + g * 8);

    f32x4 o[4];
    f32x4 zz = {0.f, 0.f, 0.f, 0.f};
#pragma unroll
    for (int c = 0; c < 4; ++c) o[c] = zz;
    float m = -INFINITY, lacc = 0.f;

    const int k0 = chunk * CHUNK;
    const int kend = min(k0 + CHUNK, qw + 16);
    const int T = (kend - k0 + 31) >> 5;

    s16x8 kaA[4], kaB[4];
    vfrag vaA[NVB], vaB[NVB];
    LOAD_K(kaA, k0);
    LOAD_V(vaA, k0);

    for (int t = 0; t < T; t += 2) {
        if (t + 1 < T) { LOAD_K(kaB, k0 + (t + 1) * 32); LOAD_V(vaB, k0 + (t + 1) * 32); }
        TILE(kaA, vaA, k0 + t * 32);
        if (t + 1 >= T) break;
        if (t + 2 < T) { LOAD_K(kaA, k0 + (t + 2) * 32); LOAD_V(vaA, k0 + (t + 2) * 32); }
        TILE(kaB, vaB, k0 + (t + 1) * 32);
    }

    if (direct) {
        const float inv = 1.0f / lacc;
        float* ob = out + base + (long)(qw + l15) * H_DIM;
#pragma unroll
        for (int c = 0; c < 4; ++c) {
            float4 st; st.x = o[c][0] * inv; st.y = o[c][1] * inv;
            st.z = o[c][2] * inv; st.w = o[c][3] * inv;
            *(float4*)(ob + c * 16 + 4 * g) = st;
        }
    } else {
        const long slot = ((long)batch * 256 + qt) * gridDim.x + chunk;
        float* pb = partO + (slot * 16 + l15) * 64;
#pragma unroll
        for (int c = 0; c < 4; ++c) {
            float4 st; st.x = o[c][0]; st.y = o[c][1];
            st.z = o[c][2]; st.w = o[c][3];
            *(float4*)(pb + c * 16 + 4 * g) = st;
        }
        if (lane < 16) {
            float2 s2; s2.x = m; s2.y = lacc;
            *(float2*)(stats2 + (slot * 16 + l15) * 2) = s2;
        }
    }
}

// ---------------------------------------------------------------------------
// Kernel 3: split-K combine (exp2 domain).
// ---------------------------------------------------------------------------
__global__ __launch_bounds__(64) void combine_kernel(
    const float* __restrict__ partO, const float* __restrict__ stats2,
    float* __restrict__ out, int CHUNK, int MAXC)
{
    const int lane = threadIdx.x;
    const int l15 = lane & 15, g = lane >> 4;
    const int qt = blockIdx.x;
    const int batch = blockIdx.y;
    const int nc = (qt * 16) / CHUNK + 1;

    f32x4 O[4];
    f32x4 zz = {0.f, 0.f, 0.f, 0.f};
#pragma unroll
    for (int i = 0; i < 4; ++i) O[i] = zz;
    float M = -INFINITY, L = 0.f;

    for (int c = 0; c < nc; ++c) {
        const long slot = ((long)batch * 256 + qt) * MAXC + c;
        const float2 s = *(const float2*)(stats2 + (slot * 16 + l15) * 2);
        const float Mn = fmaxf(M, s.x);
        const float a  = exp2f(M - Mn);
        const float bw = exp2f(s.x - Mn);
        const float* pb = partO + (slot * 16 + l15) * 64 + g * 16;
#pragma unroll
        for (int i = 0; i < 4; ++i) {
            const f32x4 oc = *(const f32x4*)(pb + 4 * i);
            O[i] = O[i] * a + oc * bw;
        }
        L = L * a + s.y * bw;
        M = Mn;
    }

    const float inv = 1.0f / L;
    float* ob = out + ((long)batch * S_LEN + qt * 16 + l15) * H_DIM + g * 16;
#pragma unroll
    for (int i = 0; i < 4; ++i) {
        float4 st; st.x = O[i][0] * inv; st.y = O[i][1] * inv;
        st.z = O[i][2] * inv; st.w = O[i][3] * inv;
        *(float4*)(ob + 4 * i) = st;
    }
}

// ---------------------------------------------------------------------------
extern "C" void kernel_launch(void* const* d_in, const int* in_sizes, int n_in,
                              void* d_out, int out_size, void* d_ws, size_t ws_size,
                              hipStream_t stream)
{
    const float* x  = (const float*)d_in[0];
    const float* Wq = (const float*)d_in[1];
    const float* bq = (const float*)d_in[2];
    const float* Wk = (const float*)d_in[3];
    const float* bk = (const float*)d_in[4];
    const float* Wv = (const float*)d_in[5];
    const float* bv = (const float*)d_in[6];
    float* out = (float*)d_out;

    const long BSH = (long)B_SZ * S_LEN * H_DIM;   // 1,048,576
    u16* qs = (u16*)d_ws;
    u16* ks = qs + BSH;
    u16* vt = ks + BSH;
    u16* wt = vt + BSH;                            // 192*1024 u16

    // Partials start at 8 MiB (past qs/ks/vt/wt = ~6.7 MiB).
    const size_t PART_OFF = (size_t)8 << 20;
    // Pick smallest CHUNK whose dense partial array fits in the workspace:
    // slots = 1024 * (4096/CHUNK); bytes = slots * (16*64*4 + 16*2*4) = slots*4224.
    int CHUNK = 4096;
    {
        const int cand[3] = {512, 1024, 2048};
        for (int i = 0; i < 3; ++i) {
            const size_t slots = (size_t)1024 * (S_LEN / cand[i]);
            if (PART_OFF + slots * 4224 <= ws_size) { CHUNK = cand[i]; break; }
        }
    }
    const int MAXC = S_LEN / CHUNK;
    const int direct = (MAXC == 1);
    const size_t slots = (size_t)1024 * MAXC;
    float* partO  = (float*)((char*)d_ws + PART_OFF);
    float* stats2 = partO + slots * 1024;          // slots*16*64 floats

    wt_kernel<<<768, 256, 0, stream>>>(Wq, Wk, Wv, wt);
    proj_kernel<<<B_SZ * S_LEN / 16, 256, 0, stream>>>(x, wt, bq, bk, bv, qs, ks, vt);
    attn_kernel<<<dim3(MAXC, 256, B_SZ), 64, 0, stream>>>(
        qs, ks, vt, out, partO, stats2, CHUNK, direct);
    if (!direct)
        combine_kernel<<<dim3(256, B_SZ), 64, 0, stream>>>(partO, stats2, out, CHUNK, MAXC);
}

// Round 5
// 179.487 us; speedup vs baseline: 1.4653x; 1.4653x over previous
//
#include <hip/hip_runtime.h>
#include <math.h>

#define E_DIM 1024
#define H_DIM 64
#define S_LEN 4096
#define B_SZ  4

typedef short s16x8 __attribute__((ext_vector_type(8)));
typedef short s16x4 __attribute__((ext_vector_type(4)));
typedef float f32x4 __attribute__((ext_vector_type(4)));
typedef unsigned short u16;
typedef unsigned int u32;

// q is pre-scaled by 1/sqrt(H) * log2(e) so attention uses exp2 throughout.
#define QSCALE 0.180336880f
#define CHUNK  512
#define MAXC   8      // S_LEN / CHUNK

static __device__ __forceinline__ u16 f2b(float f) {
    u32 u = __builtin_bit_cast(u32, f);
    u += 0x7fffu + ((u >> 16) & 1u);        // RNE
    return (u16)(u >> 16);
}
static __device__ __forceinline__ u32 pk2(float lo, float hi) {
    return (u32)f2b(lo) | ((u32)f2b(hi) << 16);
}

#if defined(__has_builtin)
#  if __has_builtin(__builtin_amdgcn_mfma_f32_16x16x16bf16_1k)
#    define USE_1K 1
#  else
#    define USE_1K 0
#  endif
#else
#  define USE_1K 0
#endif

// ---------------------------------------------------------------------------
// Kernel 0: W transpose + bf16 convert.  Wt[mat*64+h][k] = bf16(W_mat[k][h])
// ---------------------------------------------------------------------------
__global__ __launch_bounds__(256) void wt_kernel(
    const float* __restrict__ Wq, const float* __restrict__ Wk,
    const float* __restrict__ Wv, u16* __restrict__ wt)
{
    const int flat = blockIdx.x * 256 + threadIdx.x;   // 0..196607
    const int mat = flat >> 16;
    const int within = flat & 65535;                   // = k*64 + h
    const int kk = within >> 6;
    const int h  = within & 63;
    const float* W = (mat == 0) ? Wq : (mat == 1) ? Wk : Wv;
    wt[(long)(mat * 64 + h) * E_DIM + kk] = f2b(W[within]);
}

// ---------------------------------------------------------------------------
// Kernel 1: QKV projection via MFMA, E-split across 4 waves + LDS reduce.
// q stored row-major bf16 PRE-SCALED by QSCALE; k row-major; v transposed
// Vt[b][h][s] bf16.
// ---------------------------------------------------------------------------
__global__ __launch_bounds__(256) void proj_kernel(
    const float* __restrict__ x, const u16* __restrict__ wt,
    const float* __restrict__ bq, const float* __restrict__ bk,
    const float* __restrict__ bv,
    u16* __restrict__ qs, u16* __restrict__ ks, u16* __restrict__ vt)
{
    __shared__ f32x4 red[4][12][64];

    const int tid = threadIdx.x;
    const int w    = tid >> 6;
    const int lane = tid & 63;
    const int l15 = lane & 15, g = lane >> 4;
    const long row0 = (long)blockIdx.x * 16;
    const float* xr = x + (row0 + l15) * E_DIM + w * 256;

    f32x4 z = {0.f, 0.f, 0.f, 0.f};
    f32x4 o[12];
#pragma unroll
    for (int i = 0; i < 12; ++i) o[i] = z;

#pragma unroll
    for (int ke = 0; ke < 256; ke += 32) {
        const float4 fa = *(const float4*)(xr + ke + g * 8);
        const float4 fb = *(const float4*)(xr + ke + g * 8 + 4);
        s16x8 xa;
        xa[0] = (short)f2b(fa.x); xa[1] = (short)f2b(fa.y);
        xa[2] = (short)f2b(fa.z); xa[3] = (short)f2b(fa.w);
        xa[4] = (short)f2b(fb.x); xa[5] = (short)f2b(fb.y);
        xa[6] = (short)f2b(fb.z); xa[7] = (short)f2b(fb.w);
#pragma unroll
        for (int mh = 0; mh < 12; ++mh) {
            const s16x8 wa = *(const s16x8*)(
                wt + (long)(mh * 16 + l15) * E_DIM + w * 256 + ke + g * 8);
            o[mh] = __builtin_amdgcn_mfma_f32_16x16x32_bf16(wa, xa, o[mh], 0, 0, 0);
        }
    }

#pragma unroll
    for (int mh = 0; mh < 12; ++mh) red[w][mh][lane] = o[mh];
    __syncthreads();

    const long rg = row0 + l15;
    const int batch = (int)(rg >> 12);
    const int sl = (int)(rg & 4095);

#pragma unroll
    for (int i = 0; i < 3; ++i) {
        const int mh = w * 3 + i;
        const int mat = mh >> 2, hb = mh & 3;
        f32x4 s = red[0][mh][lane];
        s += red[1][mh][lane];
        s += red[2][mh][lane];
        s += red[3][mh][lane];
        const float* bias = (mat == 0) ? bq : (mat == 1) ? bk : bv;
        const float4 bb = *(const float4*)(bias + hb * 16 + 4 * g);
        float r0 = s[0] + bb.x, r1 = s[1] + bb.y;
        float r2 = s[2] + bb.z, r3 = s[3] + bb.w;
        if (mat == 0) {
            r0 *= QSCALE; r1 *= QSCALE; r2 *= QSCALE; r3 *= QSCALE;
            uint2 pk; pk.x = pk2(r0, r1); pk.y = pk2(r2, r3);
            *(uint2*)(qs + rg * H_DIM + hb * 16 + 4 * g) = pk;
        } else if (mat == 1) {
            uint2 pk; pk.x = pk2(r0, r1); pk.y = pk2(r2, r3);
            *(uint2*)(ks + rg * H_DIM + hb * 16 + 4 * g) = pk;
        } else {
            const long hbase = (long)batch * H_DIM + hb * 16 + 4 * g;
            vt[(hbase + 0) * S_LEN + sl] = f2b(r0);
            vt[(hbase + 1) * S_LEN + sl] = f2b(r1);
            vt[(hbase + 2) * S_LEN + sl] = f2b(r2);
            vt[(hbase + 3) * S_LEN + sl] = f2b(r3);
        }
    }
}

// ---------------------------------------------------------------------------
// Per-wave flash-attention routine (verified round 3/4). Zero LDS/barriers.
// QK^T transposed (mfma(K,Q)): D col = q = l15, row = key = 4g+r.
// PV as O^T = V^T . P^T so D col = q: rescale and 1/l are own-lane ops.
// ---------------------------------------------------------------------------
#if USE_1K
typedef s16x4 vfrag;
#define NVB 8
#else
typedef s16x8 vfrag;
#define NVB 4
#endif

#define LOAD_K(KA, kv0_) do { \
    KA[0] = *(const s16x8*)(kb + (long)((kv0_) + l15) * H_DIM + g * 8); \
    KA[1] = *(const s16x8*)(kb + (long)((kv0_) + l15) * H_DIM + 32 + g * 8); \
    KA[2] = *(const s16x8*)(kb + (long)((kv0_) + 16 + l15) * H_DIM + g * 8); \
    KA[3] = *(const s16x8*)(kb + (long)((kv0_) + 16 + l15) * H_DIM + 32 + g * 8); \
} while (0)

#if USE_1K
#define LOAD_V(VA, kv0_) do { \
    _Pragma("unroll") \
    for (int c = 0; c < 4; ++c) { \
        VA[2*c]   = *(const s16x4*)(vtb + (long)(c * 16 + l15) * S_LEN + (kv0_) + 4 * g); \
        VA[2*c+1] = *(const s16x4*)(vtb + (long)(c * 16 + l15) * S_LEN + (kv0_) + 16 + 4 * g); \
    } \
} while (0)
#define PV(VA) do { \
    s16x4 pa0, pa1; \
    pa0[0] = (short)f2b(p[0]); pa0[1] = (short)f2b(p[1]); \
    pa0[2] = (short)f2b(p[2]); pa0[3] = (short)f2b(p[3]); \
    pa1[0] = (short)f2b(p[4]); pa1[1] = (short)f2b(p[5]); \
    pa1[2] = (short)f2b(p[6]); pa1[3] = (short)f2b(p[7]); \
    _Pragma("unroll") \
    for (int c = 0; c < 4; ++c) { \
        o[c] = __builtin_amdgcn_mfma_f32_16x16x16bf16_1k(VA[2*c],   pa0, o[c], 0, 0, 0); \
        o[c] = __builtin_amdgcn_mfma_f32_16x16x16bf16_1k(VA[2*c+1], pa1, o[c], 0, 0, 0); \
    } \
} while (0)
#else
#define LOAD_V(VA, kv0_) do { \
    _Pragma("unroll") \
    for (int c = 0; c < 4; ++c) \
        VA[c] = *(const s16x8*)(vtb + (long)(c * 16 + l15) * S_LEN + (kv0_) + 8 * g); \
} while (0)
#define PV(VA) do { \
    const u32 w0 = pk2(p[0], p[1]), w1 = pk2(p[2], p[3]); \
    const u32 w2 = pk2(p[4], p[5]), w3 = pk2(p[6], p[7]); \
    const int srcA = ((g & 1) * 2) * 16 + l15, srcB = srcA + 16; \
    const u32 a0 = (u32)__shfl((int)w0, srcA, 64), a1 = (u32)__shfl((int)w1, srcA, 64); \
    const u32 a2 = (u32)__shfl((int)w2, srcA, 64), a3 = (u32)__shfl((int)w3, srcA, 64); \
    const u32 b0 = (u32)__shfl((int)w0, srcB, 64), b1 = (u32)__shfl((int)w1, srcB, 64); \
    const u32 b2 = (u32)__shfl((int)w2, srcB, 64), b3 = (u32)__shfl((int)w3, srcB, 64); \
    const bool losel = (g < 2); \
    const u32 d0 = losel ? a0 : a2, d1 = losel ? a1 : a3; \
    const u32 d2 = losel ? b0 : b2, d3 = losel ? b1 : b3; \
    s16x8 pa; \
    pa[0] = (short)(d0 & 0xffff); pa[1] = (short)(d0 >> 16); \
    pa[2] = (short)(d1 & 0xffff); pa[3] = (short)(d1 >> 16); \
    pa[4] = (short)(d2 & 0xffff); pa[5] = (short)(d2 >> 16); \
    pa[6] = (short)(d3 & 0xffff); pa[7] = (short)(d3 >> 16); \
    _Pragma("unroll") \
    for (int c = 0; c < 4; ++c) \
        o[c] = __builtin_amdgcn_mfma_f32_16x16x32_bf16(VA[c], pa, o[c], 0, 0, 0); \
} while (0)
#endif

#define TILE(KA, VA, kv0arg) do { \
    const int kv0 = (kv0arg); \
    f32x4 z = {0.f, 0.f, 0.f, 0.f}; \
    f32x4 st0 = __builtin_amdgcn_mfma_f32_16x16x32_bf16(KA[0], qa0, z, 0, 0, 0); \
    st0 = __builtin_amdgcn_mfma_f32_16x16x32_bf16(KA[1], qa1, st0, 0, 0, 0); \
    f32x4 st1 = __builtin_amdgcn_mfma_f32_16x16x32_bf16(KA[2], qa0, z, 0, 0, 0); \
    st1 = __builtin_amdgcn_mfma_f32_16x16x32_bf16(KA[3], qa1, st1, 0, 0, 0); \
    float p[8]; \
    if (kv0 + 31 > qw) { \
        _Pragma("unroll") \
        for (int r = 0; r < 4; ++r) { \
            p[r]     = (kv0 + 4 * g + r      <= qg) ? st0[r] : -INFINITY; \
            p[4 + r] = (kv0 + 16 + 4 * g + r <= qg) ? st1[r] : -INFINITY; \
        } \
    } else { \
        _Pragma("unroll") \
        for (int r = 0; r < 4; ++r) { p[r] = st0[r]; p[4 + r] = st1[r]; } \
    } \
    float pm = p[0]; \
    _Pragma("unroll") \
    for (int i = 1; i < 8; ++i) pm = fmaxf(pm, p[i]); \
    pm = fmaxf(pm, __shfl_xor(pm, 16, 64)); \
    pm = fmaxf(pm, __shfl_xor(pm, 32, 64)); \
    const float mnew = fmaxf(m, pm); \
    const float corr = exp2f(m - mnew); \
    float psum = 0.f; \
    _Pragma("unroll") \
    for (int i = 0; i < 8; ++i) { p[i] = exp2f(p[i] - mnew); psum += p[i]; } \
    psum += __shfl_xor(psum, 16, 64); \
    psum += __shfl_xor(psum, 32, 64); \
    lacc = lacc * corr + psum; \
    m = mnew; \
    _Pragma("unroll") \
    for (int c = 0; c < 4; ++c) { \
        o[c][0] *= corr; o[c][1] *= corr; o[c][2] *= corr; o[c][3] *= corr; \
    } \
    PV(VA); \
} while (0)

static __device__ __forceinline__ void attn_wave(
    const u16* __restrict__ q, const u16* __restrict__ k,
    const u16* __restrict__ vt, float* __restrict__ out,
    float* __restrict__ partO, float* __restrict__ stats2,
    int batch, int qt, int chunk, int chunk_sz, int direct, int lane)
{
    const int l15 = lane & 15, g = lane >> 4;
    const int qw = qt * 16;
    const int qg = qw + l15;

    const long base = (long)batch * S_LEN * H_DIM;
    const u16* kb  = k + base;
    const u16* vtb = vt + (long)batch * H_DIM * S_LEN;

    const u16* qrow = q + base + (long)(qw + l15) * H_DIM;
    const s16x8 qa0 = *(const s16x8*)(qrow + g * 8);
    const s16x8 qa1 = *(const s16x8*)(qrow + 32 + g * 8);

    f32x4 o[4];
    f32x4 zz = {0.f, 0.f, 0.f, 0.f};
#pragma unroll
    for (int c = 0; c < 4; ++c) o[c] = zz;
    float m = -INFINITY, lacc = 0.f;

    const int k0 = chunk * chunk_sz;
    const int kend = min(k0 + chunk_sz, qw + 16);
    const int T = (kend - k0 + 31) >> 5;

    s16x8 kaA[4], kaB[4];
    vfrag vaA[NVB], vaB[NVB];
    LOAD_K(kaA, k0);
    LOAD_V(vaA, k0);

    for (int t = 0; t < T; t += 2) {
        if (t + 1 < T) { LOAD_K(kaB, k0 + (t + 1) * 32); LOAD_V(vaB, k0 + (t + 1) * 32); }
        TILE(kaA, vaA, k0 + t * 32);
        if (t + 1 >= T) break;
        if (t + 2 < T) { LOAD_K(kaA, k0 + (t + 2) * 32); LOAD_V(vaA, k0 + (t + 2) * 32); }
        TILE(kaB, vaB, k0 + (t + 1) * 32);
    }

    if (direct) {
        const float inv = 1.0f / lacc;
        float* ob = out + base + (long)(qw + l15) * H_DIM;
#pragma unroll
        for (int c = 0; c < 4; ++c) {
            float4 st; st.x = o[c][0] * inv; st.y = o[c][1] * inv;
            st.z = o[c][2] * inv; st.w = o[c][3] * inv;
            *(float4*)(ob + c * 16 + 4 * g) = st;
        }
    } else {
        const long slot = ((long)batch * 256 + qt) * MAXC + chunk;
        float* pb = partO + (slot * 16 + l15) * 64;
#pragma unroll
        for (int c = 0; c < 4; ++c) {
            float4 st; st.x = o[c][0]; st.y = o[c][1];
            st.z = o[c][2]; st.w = o[c][3];
            *(float4*)(pb + c * 16 + 4 * g) = st;
        }
        if (lane < 16) {
            float2 s2; s2.x = m; s2.y = lacc;
            *(float2*)(stats2 + (slot * 16 + l15) * 2) = s2;
        }
    }
}

// ---------------------------------------------------------------------------
// Kernel 2: packed split-K attention. 1152 blocks x 4 waves, zero idle waves.
// batch = bid&3 (one batch per XCD -> K/V L2-resident); wave r = (bid>>2)*4+wv
// enumerates the 1152 active (chunk, qt) pairs of one batch:
//   chunk c has 256-32c waves (qt = 32c..255), prefix offsets below.
// mode=0 (fallback): 256 blocks, r = qt, single chunk of 4096.
// ---------------------------------------------------------------------------
__global__ __launch_bounds__(256) void attn_split_kernel(
    const u16* __restrict__ q, const u16* __restrict__ k,
    const u16* __restrict__ vt, float* __restrict__ out,
    float* __restrict__ partO, float* __restrict__ stats2, int mode)
{
    const int wv   = threadIdx.x >> 6;
    const int lane = threadIdx.x & 63;
    const int bid  = blockIdx.x;
    const int batch = bid & 3;
    const int r = (bid >> 2) * 4 + wv;

    int c, qt;
    if (mode) {
        int base;
        if      (r < 256)  { c = 0; base = 0;    }
        else if (r < 480)  { c = 1; base = 256;  }
        else if (r < 672)  { c = 2; base = 480;  }
        else if (r < 832)  { c = 3; base = 672;  }
        else if (r < 960)  { c = 4; base = 832;  }
        else if (r < 1056) { c = 5; base = 960;  }
        else if (r < 1120) { c = 6; base = 1056; }
        else               { c = 7; base = 1120; }
        qt = 32 * c + (r - base);
        attn_wave(q, k, vt, out, partO, stats2, batch, qt, c, CHUNK, 0, lane);
    } else {
        attn_wave(q, k, vt, out, partO, stats2, batch, r, 0, S_LEN, 1, lane);
    }
}

// ---------------------------------------------------------------------------
// Kernel 3: split-K combine (exp2 domain). 256 blocks x 4 waves, wave = one
// (batch = bid&3, qt = (bid>>2)*4+wv) row-tile.
// ---------------------------------------------------------------------------
__global__ __launch_bounds__(256) void combine_kernel(
    const float* __restrict__ partO, const float* __restrict__ stats2,
    float* __restrict__ out)
{
    const int wv   = threadIdx.x >> 6;
    const int lane = threadIdx.x & 63;
    const int l15 = lane & 15, g = lane >> 4;
    const int bid = blockIdx.x;
    const int batch = bid & 3;
    const int qt = (bid >> 2) * 4 + wv;
    const int nc = (qt * 16) / CHUNK + 1;

    f32x4 O[4];
    f32x4 zz = {0.f, 0.f, 0.f, 0.f};
#pragma unroll
    for (int i = 0; i < 4; ++i) O[i] = zz;
    float M = -INFINITY, L = 0.f;

    for (int c = 0; c < nc; ++c) {
        const long slot = ((long)batch * 256 + qt) * MAXC + c;
        const float2 s = *(const float2*)(stats2 + (slot * 16 + l15) * 2);
        const float Mn = fmaxf(M, s.x);
        const float a  = exp2f(M - Mn);
        const float bw = exp2f(s.x - Mn);
        const float* pb = partO + (slot * 16 + l15) * 64 + g * 16;
#pragma unroll
        for (int i = 0; i < 4; ++i) {
            const f32x4 oc = *(const f32x4*)(pb + 4 * i);
            O[i] = O[i] * a + oc * bw;
        }
        L = L * a + s.y * bw;
        M = Mn;
    }

    const float inv = 1.0f / L;
    float* ob = out + ((long)batch * S_LEN + qt * 16 + l15) * H_DIM + g * 16;
#pragma unroll
    for (int i = 0; i < 4; ++i) {
        float4 st; st.x = O[i][0] * inv; st.y = O[i][1] * inv;
        st.z = O[i][2] * inv; st.w = O[i][3] * inv;
        *(float4*)(ob + 4 * i) = st;
    }
}

// ---------------------------------------------------------------------------
extern "C" void kernel_launch(void* const* d_in, const int* in_sizes, int n_in,
                              void* d_out, int out_size, void* d_ws, size_t ws_size,
                              hipStream_t stream)
{
    const float* x  = (const float*)d_in[0];
    const float* Wq = (const float*)d_in[1];
    const float* bq = (const float*)d_in[2];
    const float* Wk = (const float*)d_in[3];
    const float* bk = (const float*)d_in[4];
    const float* Wv = (const float*)d_in[5];
    const float* bv = (const float*)d_in[6];
    float* out = (float*)d_out;

    const long BSH = (long)B_SZ * S_LEN * H_DIM;   // 1,048,576
    u16* qs = (u16*)d_ws;
    u16* ks = qs + BSH;
    u16* vt = ks + BSH;
    u16* wt = vt + BSH;                            // 192*1024 u16

    // Partials start at 8 MiB. Dense slot array: 1024*8 slots * 4224 B.
    const size_t PART_OFF = (size_t)8 << 20;
    const size_t slots = (size_t)1024 * MAXC;
    const int split_ok = (PART_OFF + slots * 4224 <= ws_size);
    float* partO  = (float*)((char*)d_ws + PART_OFF);
    float* stats2 = partO + slots * 1024;

    wt_kernel<<<768, 256, 0, stream>>>(Wq, Wk, Wv, wt);
    proj_kernel<<<B_SZ * S_LEN / 16, 256, 0, stream>>>(x, wt, bq, bk, bv, qs, ks, vt);
    if (split_ok) {
        attn_split_kernel<<<1152, 256, 0, stream>>>(qs, ks, vt, out, partO, stats2, 1);
        combine_kernel<<<256, 256, 0, stream>>>(partO, stats2, out);
    } else {
        attn_split_kernel<<<256, 256, 0, stream>>>(qs, ks, vt, out, partO, stats2, 0);
    }
}

// Round 6
// 114.586 us; speedup vs baseline: 2.2953x; 1.5664x over previous
//
#include <hip/hip_runtime.h>
#include <math.h>

#define E_DIM 1024
#define H_DIM 64
#define S_LEN 4096
#define B_SZ  4

typedef short s16x8 __attribute__((ext_vector_type(8)));
typedef short s16x4 __attribute__((ext_vector_type(4)));
typedef float f32x4 __attribute__((ext_vector_type(4)));
typedef unsigned short u16;
typedef unsigned int u32;

// q is pre-scaled by 1/sqrt(H) * log2(e) so attention uses exp2 throughout.
#define QSCALE 0.180336880f
#define CHUNK  512
#define MAXC   8      // S_LEN / CHUNK
#define KB     64     // keys per staged LDS tile

static __device__ __forceinline__ u16 f2b(float f) {
    u32 u = __builtin_bit_cast(u32, f);
    u += 0x7fffu + ((u >> 16) & 1u);        // RNE
    return (u16)(u >> 16);
}
static __device__ __forceinline__ u32 pk2(float lo, float hi) {
    return (u32)f2b(lo) | ((u32)f2b(hi) << 16);
}

// async global->LDS, 16B per lane; HW dest = wave-uniform base + lane*16
static __device__ __forceinline__ void gload16(const void* g, void* l) {
    __builtin_amdgcn_global_load_lds(
        (const __attribute__((address_space(1))) u32*)g,
        (__attribute__((address_space(3))) u32*)l, 16, 0, 0);
}

#if defined(__has_builtin)
#  if __has_builtin(__builtin_amdgcn_mfma_f32_16x16x16bf16_1k)
#    define USE_1K 1
#  else
#    define USE_1K 0
#  endif
#else
#  define USE_1K 0
#endif

// ---------------------------------------------------------------------------
// Kernel 0: W -> bf16, FRAG-ORDERED layout. For frag (mh, kestep) the 64
// lanes' 8 elems are contiguous: wt2[((mh*32+kestep)*64 + lane)*8 + j]
// where lane = (g<<4)|l15, row h = mh*16+l15, e = kestep*32 + g*8 + j.
// ---------------------------------------------------------------------------
__global__ __launch_bounds__(256) void wt_kernel(
    const float* __restrict__ Wq, const float* __restrict__ Wk,
    const float* __restrict__ Wv, u16* __restrict__ wt)
{
    const int flat = blockIdx.x * 256 + threadIdx.x;   // 0..196607
    const int mat = flat >> 16;
    const int within = flat & 65535;                   // = k*64 + h
    const int kk = within >> 6;
    const int h  = within & 63;
    const float* W = (mat == 0) ? Wq : (mat == 1) ? Wk : Wv;
    const int mh = mat * 4 + (h >> 4);
    const int lane = (((kk >> 3) & 3) << 4) | (h & 15);
    const long idx = (long)mh * 16384 + (long)(kk >> 5) * 512 + lane * 8 + (kk & 7);
    wt[idx] = f2b(W[within]);
}

// ---------------------------------------------------------------------------
// Kernel 1: QKV projection via MFMA, E-split across 4 waves + LDS reduce.
// wa loads are now contiguous 16B/lane (frag-ordered wt2).
// q bf16 row-major PRE-SCALED by QSCALE; k row-major; v transposed Vt[b][h][s].
// ---------------------------------------------------------------------------
__global__ __launch_bounds__(256) void proj_kernel(
    const float* __restrict__ x, const u16* __restrict__ wt,
    const float* __restrict__ bq, const float* __restrict__ bk,
    const float* __restrict__ bv,
    u16* __restrict__ qs, u16* __restrict__ ks, u16* __restrict__ vt)
{
    __shared__ f32x4 red[4][12][64];

    const int tid = threadIdx.x;
    const int w    = tid >> 6;
    const int lane = tid & 63;
    const int l15 = lane & 15, g = lane >> 4;
    const long row0 = (long)blockIdx.x * 16;
    const float* xr = x + (row0 + l15) * E_DIM + w * 256;

    f32x4 z = {0.f, 0.f, 0.f, 0.f};
    f32x4 o[12];
#pragma unroll
    for (int i = 0; i < 12; ++i) o[i] = z;

#pragma unroll
    for (int ke = 0; ke < 256; ke += 32) {
        const float4 fa = *(const float4*)(xr + ke + g * 8);
        const float4 fb = *(const float4*)(xr + ke + g * 8 + 4);
        s16x8 xa;
        xa[0] = (short)f2b(fa.x); xa[1] = (short)f2b(fa.y);
        xa[2] = (short)f2b(fa.z); xa[3] = (short)f2b(fa.w);
        xa[4] = (short)f2b(fb.x); xa[5] = (short)f2b(fb.y);
        xa[6] = (short)f2b(fb.z); xa[7] = (short)f2b(fb.w);
#pragma unroll
        for (int mh = 0; mh < 12; ++mh) {
            const s16x8 wa = *(const s16x8*)(
                wt + (long)mh * 16384 + (long)(w * 8 + (ke >> 5)) * 512 + lane * 8);
            o[mh] = __builtin_amdgcn_mfma_f32_16x16x32_bf16(wa, xa, o[mh], 0, 0, 0);
        }
    }

#pragma unroll
    for (int mh = 0; mh < 12; ++mh) red[w][mh][lane] = o[mh];
    __syncthreads();

    const long rg = row0 + l15;
    const int batch = (int)(rg >> 12);
    const int sl = (int)(rg & 4095);

#pragma unroll
    for (int i = 0; i < 3; ++i) {
        const int mh = w * 3 + i;
        const int mat = mh >> 2, hb = mh & 3;
        f32x4 s = red[0][mh][lane];
        s += red[1][mh][lane];
        s += red[2][mh][lane];
        s += red[3][mh][lane];
        const float* bias = (mat == 0) ? bq : (mat == 1) ? bk : bv;
        const float4 bb = *(const float4*)(bias + hb * 16 + 4 * g);
        float r0 = s[0] + bb.x, r1 = s[1] + bb.y;
        float r2 = s[2] + bb.z, r3 = s[3] + bb.w;
        if (mat == 0) {
            r0 *= QSCALE; r1 *= QSCALE; r2 *= QSCALE; r3 *= QSCALE;
            uint2 pk; pk.x = pk2(r0, r1); pk.y = pk2(r2, r3);
            *(uint2*)(qs + rg * H_DIM + hb * 16 + 4 * g) = pk;
        } else if (mat == 1) {
            uint2 pk; pk.x = pk2(r0, r1); pk.y = pk2(r2, r3);
            *(uint2*)(ks + rg * H_DIM + hb * 16 + 4 * g) = pk;
        } else {
            const long hbase = (long)batch * H_DIM + hb * 16 + 4 * g;
            vt[(hbase + 0) * S_LEN + sl] = f2b(r0);
            vt[(hbase + 1) * S_LEN + sl] = f2b(r1);
            vt[(hbase + 2) * S_LEN + sl] = f2b(r2);
            vt[(hbase + 3) * S_LEN + sl] = f2b(r3);
        }
    }
}

// ---------------------------------------------------------------------------
// Kernel 2: LDS-staged split-K causal flash attention.
// Block = 4 waves x 16 q-rows = 64 q-rows of one batch; grid enumerates the
// 1152 active (batch, qgroup, chunk) blocks (CHUNK=512, zero idle blocks).
// Per 64-key tile: K[64][128B] and Vt[64h][128B] staged ONCE per block via
// global_load_lds (dense 1KB/instr; global source pre-XOR-swizzled so LDS
// holds the bank-balanced layout). Double-buffered, 1 barrier/tile.
// QK^T transposed (mfma(K,Q)): D col = q = l15. PV as O^T = V^T.P^T:
// softmax stats and rescale are own-lane ops.  Partials layout and combine
// are identical to round 5 (verified).
// ---------------------------------------------------------------------------
__global__ __launch_bounds__(256) void attn_stage_kernel(
    const u16* __restrict__ q, const u16* __restrict__ k,
    const u16* __restrict__ vt, float* __restrict__ out,
    float* __restrict__ partO, float* __restrict__ stats2, int mode)
{
    __shared__ __align__(1024) char smem[32768];   // 2 bufs x (8KB K + 8KB V)

    const int tid  = threadIdx.x;
    const int w    = tid >> 6;
    const int lane = tid & 63;
    const int l15 = lane & 15, g = lane >> 4;
    const int h7  = l15 & 7;
    const int bid = blockIdx.x;
    const int batch = bid & 3;          // bid%8 -> XCD: 2 XCDs per batch
    const int r = bid >> 2;

    int qg, c;
    if (mode) {                          // prefix-decode r -> (qg, c)
        if      (r < 8)   { qg = r;                  c = 0;      }
        else if (r < 24)  { int rr = r - 8;   qg = 8  + rr / 2; c = rr % 2; }
        else if (r < 48)  { int rr = r - 24;  qg = 16 + rr / 3; c = rr % 3; }
        else if (r < 80)  { int rr = r - 48;  qg = 24 + rr / 4; c = rr % 4; }
        else if (r < 120) { int rr = r - 80;  qg = 32 + rr / 5; c = rr % 5; }
        else if (r < 168) { int rr = r - 120; qg = 40 + rr / 6; c = rr % 6; }
        else if (r < 224) { int rr = r - 168; qg = 48 + rr / 7; c = rr % 7; }
        else              { int rr = r - 224; qg = 56 + rr / 8; c = rr % 8; }
    } else { qg = r; c = 0; }

    const int chunk_sz = mode ? CHUNK : S_LEN;
    const int qt = 4 * qg + w;
    const int qw = qt * 16;
    const int k0 = c * CHUNK;
    const int kend = min(k0 + chunk_sz, qg * 64 + 64);
    const int T = (kend - k0 + KB - 1) >> 6;
    const bool active = (k0 <= qw + 15);

    const long base = (long)batch * S_LEN * H_DIM;
    const char* kg = (const char*)(k + base);
    const char* vg = (const char*)(vt + (long)batch * H_DIM * S_LEN);

    const u16* qrow = q + base + (long)(qw + l15) * H_DIM;
    const s16x8 qa0 = *(const s16x8*)(qrow + g * 8);
    const s16x8 qa1 = *(const s16x8*)(qrow + 32 + g * 8);

    f32x4 o[4];
    f32x4 zz = {0.f, 0.f, 0.f, 0.f};
#pragma unroll
    for (int cc = 0; cc < 4; ++cc) o[cc] = zz;
    float m = -INFINITY, lacc = 0.f;
    const int qglane = qw + l15;

    // staging lane mapping: row-within-8 = lane>>3, pre-swizzled source slot
    const int srow  = lane >> 3;
    const int sslot = (lane & 7) ^ srow;

#define STAGE(bufb, kv0_) do {                                               \
    char* kd = smem + (bufb) + 2048 * w;                                     \
    const long krw = (long)((kv0_) + 16 * w + srow);                         \
    gload16(kg + krw * 128 + (sslot << 4), kd);                              \
    gload16(kg + (krw + 8) * 128 + (sslot << 4), kd + 1024);                 \
    char* vd = smem + (bufb) + 8192 + 2048 * w;                              \
    const long vrw = (long)(16 * w + srow);                                  \
    const long vco = (long)(kv0_) * 2 + (sslot << 4);                        \
    gload16(vg + vrw * 8192 + vco, vd);                                      \
    gload16(vg + (vrw + 8) * 8192 + vco, vd + 1024);                         \
} while (0)

    STAGE(0, k0);
    __syncthreads();

    for (int t = 0; t < T; ++t) {
        const int cb  = (t & 1) << 14;
        const int kv0 = k0 + t * KB;
        if (t + 1 < T) STAGE(cb ^ 16384, kv0 + KB);

        if (active && kv0 <= qw + 15) {
            const char* Kb = smem + cb;
            const char* Vb = smem + cb + 8192;
            f32x4 st[4];
#pragma unroll
            for (int kt = 0; kt < 4; ++kt) {
                const int rb = (kt * 16 + l15) * 128;
                const s16x8 ka0 = *(const s16x8*)(Kb + rb + ((g ^ h7) << 4));
                const s16x8 ka1 = *(const s16x8*)(Kb + rb + (((4 + g) ^ h7) << 4));
                st[kt] = __builtin_amdgcn_mfma_f32_16x16x32_bf16(ka0, qa0, zz, 0, 0, 0);
                st[kt] = __builtin_amdgcn_mfma_f32_16x16x32_bf16(ka1, qa1, st[kt], 0, 0, 0);
            }
            float p[16];
            if (kv0 + KB - 1 > qw) {
#pragma unroll
                for (int kt = 0; kt < 4; ++kt)
#pragma unroll
                    for (int rr2 = 0; rr2 < 4; ++rr2)
                        p[kt * 4 + rr2] =
                            (kv0 + kt * 16 + 4 * g + rr2 <= qglane) ? st[kt][rr2] : -INFINITY;
            } else {
#pragma unroll
                for (int i = 0; i < 16; ++i) p[i] = st[i >> 2][i & 3];
            }
            float pm = p[0];
#pragma unroll
            for (int i = 1; i < 16; ++i) pm = fmaxf(pm, p[i]);
            pm = fmaxf(pm, __shfl_xor(pm, 16, 64));
            pm = fmaxf(pm, __shfl_xor(pm, 32, 64));
            const float mnew = fmaxf(m, pm);
            const float corr = exp2f(m - mnew);
            float psum = 0.f;
#pragma unroll
            for (int i = 0; i < 16; ++i) { p[i] = exp2f(p[i] - mnew); psum += p[i]; }
            psum += __shfl_xor(psum, 16, 64);
            psum += __shfl_xor(psum, 32, 64);
            lacc = lacc * corr + psum;
            m = mnew;
#pragma unroll
            for (int cc = 0; cc < 4; ++cc) {
                o[cc][0] *= corr; o[cc][1] *= corr; o[cc][2] *= corr; o[cc][3] *= corr;
            }
#if USE_1K
#pragma unroll
            for (int kt = 0; kt < 4; ++kt) {
                s16x4 pa;
                pa[0] = (short)f2b(p[kt * 4 + 0]); pa[1] = (short)f2b(p[kt * 4 + 1]);
                pa[2] = (short)f2b(p[kt * 4 + 2]); pa[3] = (short)f2b(p[kt * 4 + 3]);
                const int so = (((kt * 2 + (g >> 1)) ^ h7) << 4) + (g & 1) * 8;
#pragma unroll
                for (int cc = 0; cc < 4; ++cc) {
                    const s16x4 va = *(const s16x4*)(Vb + (cc * 16 + l15) * 128 + so);
                    o[cc] = __builtin_amdgcn_mfma_f32_16x16x16bf16_1k(va, pa, o[cc], 0, 0, 0);
                }
            }
#else
#pragma unroll
            for (int hh = 0; hh < 2; ++hh) {
                const u32 w0 = pk2(p[8*hh+0], p[8*hh+1]), w1 = pk2(p[8*hh+2], p[8*hh+3]);
                const u32 w2 = pk2(p[8*hh+4], p[8*hh+5]), w3 = pk2(p[8*hh+6], p[8*hh+7]);
                const int srcA = ((g & 1) * 2) * 16 + l15, srcB = srcA + 16;
                const u32 a0 = (u32)__shfl((int)w0, srcA, 64), a1 = (u32)__shfl((int)w1, srcA, 64);
                const u32 a2 = (u32)__shfl((int)w2, srcA, 64), a3 = (u32)__shfl((int)w3, srcA, 64);
                const u32 b0 = (u32)__shfl((int)w0, srcB, 64), b1 = (u32)__shfl((int)w1, srcB, 64);
                const u32 b2 = (u32)__shfl((int)w2, srcB, 64), b3 = (u32)__shfl((int)w3, srcB, 64);
                const bool losel = (g < 2);
                const u32 d0 = losel ? a0 : a2, d1 = losel ? a1 : a3;
                const u32 d2 = losel ? b0 : b2, d3 = losel ? b1 : b3;
                s16x8 pa;
                pa[0] = (short)(d0 & 0xffff); pa[1] = (short)(d0 >> 16);
                pa[2] = (short)(d1 & 0xffff); pa[3] = (short)(d1 >> 16);
                pa[4] = (short)(d2 & 0xffff); pa[5] = (short)(d2 >> 16);
                pa[6] = (short)(d3 & 0xffff); pa[7] = (short)(d3 >> 16);
                const int so = ((hh * 4 + g) ^ h7) << 4;
#pragma unroll
                for (int cc = 0; cc < 4; ++cc) {
                    const s16x8 va = *(const s16x8*)(Vb + (cc * 16 + l15) * 128 + so);
                    o[cc] = __builtin_amdgcn_mfma_f32_16x16x32_bf16(va, pa, o[cc], 0, 0, 0);
                }
            }
#endif
        }
        __syncthreads();   // drains staging vmcnt + guards buffer reuse
    }
#undef STAGE

    if (active) {
        if (mode) {
            const long slot = ((long)batch * 256 + qt) * MAXC + c;
            float* pb = partO + (slot * 16 + l15) * 64;
#pragma unroll
            for (int cc = 0; cc < 4; ++cc) {
                float4 stv; stv.x = o[cc][0]; stv.y = o[cc][1];
                stv.z = o[cc][2]; stv.w = o[cc][3];
                *(float4*)(pb + cc * 16 + 4 * g) = stv;
            }
            if (lane < 16) {
                float2 s2; s2.x = m; s2.y = lacc;
                *(float2*)(stats2 + (slot * 16 + l15) * 2) = s2;
            }
        } else {
            const float inv = 1.0f / lacc;
            float* ob = out + base + (long)(qw + l15) * H_DIM;
#pragma unroll
            for (int cc = 0; cc < 4; ++cc) {
                float4 stv; stv.x = o[cc][0] * inv; stv.y = o[cc][1] * inv;
                stv.z = o[cc][2] * inv; stv.w = o[cc][3] * inv;
                *(float4*)(ob + cc * 16 + 4 * g) = stv;
            }
        }
    }
}

// ---------------------------------------------------------------------------
// Kernel 3: split-K combine (exp2 domain). Unchanged from round 5.
// ---------------------------------------------------------------------------
__global__ __launch_bounds__(256) void combine_kernel(
    const float* __restrict__ partO, const float* __restrict__ stats2,
    float* __restrict__ out)
{
    const int wv   = threadIdx.x >> 6;
    const int lane = threadIdx.x & 63;
    const int l15 = lane & 15, g = lane >> 4;
    const int bid = blockIdx.x;
    const int batch = bid & 3;
    const int qt = (bid >> 2) * 4 + wv;
    const int nc = (qt * 16) / CHUNK + 1;

    f32x4 O[4];
    f32x4 zz = {0.f, 0.f, 0.f, 0.f};
#pragma unroll
    for (int i = 0; i < 4; ++i) O[i] = zz;
    float M = -INFINITY, L = 0.f;

    for (int c = 0; c < nc; ++c) {
        const long slot = ((long)batch * 256 + qt) * MAXC + c;
        const float2 s = *(const float2*)(stats2 + (slot * 16 + l15) * 2);
        const float Mn = fmaxf(M, s.x);
        const float a  = exp2f(M - Mn);
        const float bw = exp2f(s.x - Mn);
        const float* pb = partO + (slot * 16 + l15) * 64 + g * 16;
#pragma unroll
        for (int i = 0; i < 4; ++i) {
            const f32x4 oc = *(const f32x4*)(pb + 4 * i);
            O[i] = O[i] * a + oc * bw;
        }
        L = L * a + s.y * bw;
        M = Mn;
    }

    const float inv = 1.0f / L;
    float* ob = out + ((long)batch * S_LEN + qt * 16 + l15) * H_DIM + g * 16;
#pragma unroll
    for (int i = 0; i < 4; ++i) {
        float4 st; st.x = O[i][0] * inv; st.y = O[i][1] * inv;
        st.z = O[i][2] * inv; st.w = O[i][3] * inv;
        *(float4*)(ob + 4 * i) = st;
    }
}

// ---------------------------------------------------------------------------
extern "C" void kernel_launch(void* const* d_in, const int* in_sizes, int n_in,
                              void* d_out, int out_size, void* d_ws, size_t ws_size,
                              hipStream_t stream)
{
    const float* x  = (const float*)d_in[0];
    const float* Wq = (const float*)d_in[1];
    const float* bq = (const float*)d_in[2];
    const float* Wk = (const float*)d_in[3];
    const float* bk = (const float*)d_in[4];
    const float* Wv = (const float*)d_in[5];
    const float* bv = (const float*)d_in[6];
    float* out = (float*)d_out;

    const long BSH = (long)B_SZ * S_LEN * H_DIM;   // 1,048,576
    u16* qs = (u16*)d_ws;
    u16* ks = qs + BSH;
    u16* vt = ks + BSH;
    u16* wt = vt + BSH;                            // 192*1024 u16 (frag-ordered)

    const size_t PART_OFF = (size_t)8 << 20;
    const size_t slots = (size_t)1024 * MAXC;
    const int split_ok = (PART_OFF + slots * 4224 <= ws_size);
    float* partO  = (float*)((char*)d_ws + PART_OFF);
    float* stats2 = partO + slots * 1024;

    wt_kernel<<<768, 256, 0, stream>>>(Wq, Wk, Wv, wt);
    proj_kernel<<<B_SZ * S_LEN / 16, 256, 0, stream>>>(x, wt, bq, bk, bv, qs, ks, vt);
    if (split_ok) {
        attn_stage_kernel<<<1152, 256, 0, stream>>>(qs, ks, vt, out, partO, stats2, 1);
        combine_kernel<<<256, 256, 0, stream>>>(partO, stats2, out);
    } else {
        attn_stage_kernel<<<256, 256, 0, stream>>>(qs, ks, vt, out, partO, stats2, 0);
    }
}

// Round 7
// 78.543 us; speedup vs baseline: 3.3486x; 1.4589x over previous
//
#include <hip/hip_runtime.h>
#include <math.h>

#define E_DIM 1024
#define H_DIM 64
#define S_LEN 4096
#define B_SZ  4

typedef short s16x8 __attribute__((ext_vector_type(8)));
typedef short s16x4 __attribute__((ext_vector_type(4)));
typedef float f32x4 __attribute__((ext_vector_type(4)));
typedef unsigned short u16;
typedef unsigned int u32;

// q is pre-scaled by 1/sqrt(H) * log2(e) so attention uses exp2 throughout.
#define QSCALE 0.180336880f
#define CHUNK  512
#define MAXC   8      // S_LEN / CHUNK
#define KB     64     // keys per staged LDS tile

static __device__ __forceinline__ u16 f2b(float f) {
    u32 u = __builtin_bit_cast(u32, f);
    u += 0x7fffu + ((u >> 16) & 1u);        // RNE
    return (u16)(u >> 16);
}
static __device__ __forceinline__ u32 pk2(float lo, float hi) {
    return (u32)f2b(lo) | ((u32)f2b(hi) << 16);
}

// async global->LDS, 16B per lane; HW dest = wave-uniform base + lane*16
static __device__ __forceinline__ void gload16(const void* g, void* l) {
    __builtin_amdgcn_global_load_lds(
        (const __attribute__((address_space(1))) u32*)g,
        (__attribute__((address_space(3))) u32*)l, 16, 0, 0);
}

#if defined(__has_builtin)
#  if __has_builtin(__builtin_amdgcn_mfma_f32_16x16x16bf16_1k)
#    define USE_1K 1
#  else
#    define USE_1K 0
#  endif
#else
#  define USE_1K 0
#endif

// ---------------------------------------------------------------------------
// Kernel 0: W -> bf16, FRAG-ORDERED layout (unchanged, verified round 6).
// wt[mh*16384 + kestep*512 + lane*8 + j], lane = (g<<4)|l15,
// row h = mh*16+l15, e = kestep*32 + g*8 + j.
// ---------------------------------------------------------------------------
__global__ __launch_bounds__(256) void wt_kernel(
    const float* __restrict__ Wq, const float* __restrict__ Wk,
    const float* __restrict__ Wv, u16* __restrict__ wt)
{
    const int flat = blockIdx.x * 256 + threadIdx.x;   // 0..196607
    const int mat = flat >> 16;
    const int within = flat & 65535;                   // = k*64 + h
    const int kk = within >> 6;
    const int h  = within & 63;
    const float* W = (mat == 0) ? Wq : (mat == 1) ? Wk : Wv;
    const int mh = mat * 4 + (h >> 4);
    const int lane = (((kk >> 3) & 3) << 4) | (h & 15);
    const long idx = (long)mh * 16384 + (long)(kk >> 5) * 512 + lane * 8 + (kk & 7);
    wt[idx] = f2b(W[within]);
}

// ---------------------------------------------------------------------------
// Kernel 1: QKV projection, HBM-streamed via async global_load_lds.
// 256 blocks x 4 waves, 64 rows/block; wave w owns rows row0+w*16..+15 and a
// private 16KB LDS partition (2 x 8KB K-chunk buffers). No barriers: each
// wave stages and consumes only its own rows. Counted vmcnt(8) keeps the
// next chunk's 8 DMA loads in flight across the compute (T4).
// Outputs: q bf16 row-major PRE-SCALED by QSCALE; k row-major; v transposed
// Vt[b][h][s] bf16.
// ---------------------------------------------------------------------------
__global__ __launch_bounds__(256) void proj_kernel(
    const float* __restrict__ x, const u16* __restrict__ wt,
    const float* __restrict__ bq, const float* __restrict__ bk,
    const float* __restrict__ bv,
    u16* __restrict__ qs, u16* __restrict__ ks, u16* __restrict__ vt)
{
    __shared__ __align__(1024) char smem[65536];   // 4 waves x 2 bufs x 8KB

    const int tid  = threadIdx.x;
    const int w    = tid >> 6;
    const int lane = tid & 63;
    const int l15 = lane & 15, g = lane >> 4;
    const long row0 = (long)blockIdx.x * 64;

    char* wbase = smem + w * 16384;
    const char* xg = (const char*)(x + (row0 + w * 16) * E_DIM);
    const int srow2 = lane >> 5;         // 0..1: row-within-pair
    const int scol  = (lane & 31) << 4;  // byte offset within 512B row-chunk

    f32x4 zz = {0.f, 0.f, 0.f, 0.f};
    f32x4 o[12];
#pragma unroll
    for (int i = 0; i < 12; ++i) o[i] = zz;

    // stage chunk c (128 floats of K) into buffer b: 8 instrs x 1KB (2 rows each)
#define PSTAGE(b, c) do {                                                     \
    _Pragma("unroll")                                                         \
    for (int i = 0; i < 8; ++i) {                                             \
        const char* src = xg + ((long)(2 * i + srow2) * E_DIM + (c) * 128) * 4 \
                          + scol;                                             \
        gload16(src, wbase + (b) * 8192 + i * 1024);                          \
    }                                                                         \
} while (0)

#define PCOMP(b, c) do {                                                      \
    _Pragma("unroll")                                                         \
    for (int ke = 0; ke < 128; ke += 32) {                                    \
        const char* rp = wbase + (b) * 8192 + l15 * 512 + ke * 4 + g * 32;    \
        const float4 fa = *(const float4*)(rp);                               \
        const float4 fb = *(const float4*)(rp + 16);                          \
        s16x8 xa;                                                             \
        xa[0] = (short)f2b(fa.x); xa[1] = (short)f2b(fa.y);                   \
        xa[2] = (short)f2b(fa.z); xa[3] = (short)f2b(fa.w);                   \
        xa[4] = (short)f2b(fb.x); xa[5] = (short)f2b(fb.y);                   \
        xa[6] = (short)f2b(fb.z); xa[7] = (short)f2b(fb.w);                   \
        const int kg = (c) * 4 + (ke >> 5);                                   \
        _Pragma("unroll")                                                     \
        for (int mh = 0; mh < 12; ++mh) {                                     \
            const s16x8 wa = *(const s16x8*)(                                 \
                wt + (long)mh * 16384 + (long)kg * 512 + lane * 8);           \
            o[mh] = __builtin_amdgcn_mfma_f32_16x16x32_bf16(wa, xa, o[mh],    \
                                                            0, 0, 0);         \
        }                                                                     \
    }                                                                         \
} while (0)

    PSTAGE(0, 0);
#pragma unroll
    for (int c = 0; c < 7; ++c) {
        PSTAGE((c + 1) & 1, c + 1);
        // wait until only the 8 newest (next chunk's stage) remain in flight:
        // drains chunk c's stage + any wt-load stragglers.
        asm volatile("s_waitcnt vmcnt(8)" ::: "memory");
        __builtin_amdgcn_sched_barrier(0);
        PCOMP(c & 1, c);
    }
    asm volatile("s_waitcnt vmcnt(0)" ::: "memory");
    __builtin_amdgcn_sched_barrier(0);
    PCOMP(1, 7);
#undef PSTAGE
#undef PCOMP

    const long rg = row0 + w * 16 + l15;   // this lane's x-row (D column)
    const int batch = (int)(rg >> 12);
    const int sl = (int)(rg & 4095);
#pragma unroll
    for (int mh = 0; mh < 12; ++mh) {
        const int mat = mh >> 2, hb = mh & 3;
        const float* bias = (mat == 0) ? bq : (mat == 1) ? bk : bv;
        const float4 bb = *(const float4*)(bias + hb * 16 + 4 * g);
        float r0 = o[mh][0] + bb.x, r1 = o[mh][1] + bb.y;
        float r2 = o[mh][2] + bb.z, r3 = o[mh][3] + bb.w;
        if (mat == 0) {
            r0 *= QSCALE; r1 *= QSCALE; r2 *= QSCALE; r3 *= QSCALE;
            uint2 pk; pk.x = pk2(r0, r1); pk.y = pk2(r2, r3);
            *(uint2*)(qs + rg * H_DIM + hb * 16 + 4 * g) = pk;
        } else if (mat == 1) {
            uint2 pk; pk.x = pk2(r0, r1); pk.y = pk2(r2, r3);
            *(uint2*)(ks + rg * H_DIM + hb * 16 + 4 * g) = pk;
        } else {
            const long hbase = (long)batch * H_DIM + hb * 16 + 4 * g;
            vt[(hbase + 0) * S_LEN + sl] = f2b(r0);
            vt[(hbase + 1) * S_LEN + sl] = f2b(r1);
            vt[(hbase + 2) * S_LEN + sl] = f2b(r2);
            vt[(hbase + 3) * S_LEN + sl] = f2b(r3);
        }
    }
}

// ---------------------------------------------------------------------------
// Kernel 2: LDS-staged split-K causal flash attention (unchanged, round 6).
// ---------------------------------------------------------------------------
__global__ __launch_bounds__(256) void attn_stage_kernel(
    const u16* __restrict__ q, const u16* __restrict__ k,
    const u16* __restrict__ vt, float* __restrict__ out,
    float* __restrict__ partO, float* __restrict__ stats2, int mode)
{
    __shared__ __align__(1024) char smem[32768];   // 2 bufs x (8KB K + 8KB V)

    const int tid  = threadIdx.x;
    const int w    = tid >> 6;
    const int lane = tid & 63;
    const int l15 = lane & 15, g = lane >> 4;
    const int h7  = l15 & 7;
    const int bid = blockIdx.x;
    const int batch = bid & 3;
    const int r = bid >> 2;

    int qg, c;
    if (mode) {                          // prefix-decode r -> (qg, c)
        if      (r < 8)   { qg = r;                  c = 0;      }
        else if (r < 24)  { int rr = r - 8;   qg = 8  + rr / 2; c = rr % 2; }
        else if (r < 48)  { int rr = r - 24;  qg = 16 + rr / 3; c = rr % 3; }
        else if (r < 80)  { int rr = r - 48;  qg = 24 + rr / 4; c = rr % 4; }
        else if (r < 120) { int rr = r - 80;  qg = 32 + rr / 5; c = rr % 5; }
        else if (r < 168) { int rr = r - 120; qg = 40 + rr / 6; c = rr % 6; }
        else if (r < 224) { int rr = r - 168; qg = 48 + rr / 7; c = rr % 7; }
        else              { int rr = r - 224; qg = 56 + rr / 8; c = rr % 8; }
    } else { qg = r; c = 0; }

    const int chunk_sz = mode ? CHUNK : S_LEN;
    const int qt = 4 * qg + w;
    const int qw = qt * 16;
    const int k0 = c * CHUNK;
    const int kend = min(k0 + chunk_sz, qg * 64 + 64);
    const int T = (kend - k0 + KB - 1) >> 6;
    const bool active = (k0 <= qw + 15);

    const long base = (long)batch * S_LEN * H_DIM;
    const char* kg = (const char*)(k + base);
    const char* vg = (const char*)(vt + (long)batch * H_DIM * S_LEN);

    const u16* qrow = q + base + (long)(qw + l15) * H_DIM;
    const s16x8 qa0 = *(const s16x8*)(qrow + g * 8);
    const s16x8 qa1 = *(const s16x8*)(qrow + 32 + g * 8);

    f32x4 o[4];
    f32x4 zz = {0.f, 0.f, 0.f, 0.f};
#pragma unroll
    for (int cc = 0; cc < 4; ++cc) o[cc] = zz;
    float m = -INFINITY, lacc = 0.f;
    const int qglane = qw + l15;

    const int srow  = lane >> 3;
    const int sslot = (lane & 7) ^ srow;

#define STAGE(bufb, kv0_) do {                                               \
    char* kd = smem + (bufb) + 2048 * w;                                     \
    const long krw = (long)((kv0_) + 16 * w + srow);                         \
    gload16(kg + krw * 128 + (sslot << 4), kd);                              \
    gload16(kg + (krw + 8) * 128 + (sslot << 4), kd + 1024);                 \
    char* vd = smem + (bufb) + 8192 + 2048 * w;                              \
    const long vrw = (long)(16 * w + srow);                                  \
    const long vco = (long)(kv0_) * 2 + (sslot << 4);                        \
    gload16(vg + vrw * 8192 + vco, vd);                                      \
    gload16(vg + (vrw + 8) * 8192 + vco, vd + 1024);                         \
} while (0)

    STAGE(0, k0);
    __syncthreads();

    for (int t = 0; t < T; ++t) {
        const int cb  = (t & 1) << 14;
        const int kv0 = k0 + t * KB;
        if (t + 1 < T) STAGE(cb ^ 16384, kv0 + KB);

        if (active && kv0 <= qw + 15) {
            const char* Kb = smem + cb;
            const char* Vb = smem + cb + 8192;
            f32x4 st[4];
#pragma unroll
            for (int kt = 0; kt < 4; ++kt) {
                const int rb = (kt * 16 + l15) * 128;
                const s16x8 ka0 = *(const s16x8*)(Kb + rb + ((g ^ h7) << 4));
                const s16x8 ka1 = *(const s16x8*)(Kb + rb + (((4 + g) ^ h7) << 4));
                st[kt] = __builtin_amdgcn_mfma_f32_16x16x32_bf16(ka0, qa0, zz, 0, 0, 0);
                st[kt] = __builtin_amdgcn_mfma_f32_16x16x32_bf16(ka1, qa1, st[kt], 0, 0, 0);
            }
            float p[16];
            if (kv0 + KB - 1 > qw) {
#pragma unroll
                for (int kt = 0; kt < 4; ++kt)
#pragma unroll
                    for (int rr2 = 0; rr2 < 4; ++rr2)
                        p[kt * 4 + rr2] =
                            (kv0 + kt * 16 + 4 * g + rr2 <= qglane) ? st[kt][rr2] : -INFINITY;
            } else {
#pragma unroll
                for (int i = 0; i < 16; ++i) p[i] = st[i >> 2][i & 3];
            }
            float pm = p[0];
#pragma unroll
            for (int i = 1; i < 16; ++i) pm = fmaxf(pm, p[i]);
            pm = fmaxf(pm, __shfl_xor(pm, 16, 64));
            pm = fmaxf(pm, __shfl_xor(pm, 32, 64));
            const float mnew = fmaxf(m, pm);
            const float corr = exp2f(m - mnew);
            float psum = 0.f;
#pragma unroll
            for (int i = 0; i < 16; ++i) { p[i] = exp2f(p[i] - mnew); psum += p[i]; }
            psum += __shfl_xor(psum, 16, 64);
            psum += __shfl_xor(psum, 32, 64);
            lacc = lacc * corr + psum;
            m = mnew;
#pragma unroll
            for (int cc = 0; cc < 4; ++cc) {
                o[cc][0] *= corr; o[cc][1] *= corr; o[cc][2] *= corr; o[cc][3] *= corr;
            }
#if USE_1K
#pragma unroll
            for (int kt = 0; kt < 4; ++kt) {
                s16x4 pa;
                pa[0] = (short)f2b(p[kt * 4 + 0]); pa[1] = (short)f2b(p[kt * 4 + 1]);
                pa[2] = (short)f2b(p[kt * 4 + 2]); pa[3] = (short)f2b(p[kt * 4 + 3]);
                const int so = (((kt * 2 + (g >> 1)) ^ h7) << 4) + (g & 1) * 8;
#pragma unroll
                for (int cc = 0; cc < 4; ++cc) {
                    const s16x4 va = *(const s16x4*)(Vb + (cc * 16 + l15) * 128 + so);
                    o[cc] = __builtin_amdgcn_mfma_f32_16x16x16bf16_1k(va, pa, o[cc], 0, 0, 0);
                }
            }
#else
#pragma unroll
            for (int hh = 0; hh < 2; ++hh) {
                const u32 w0 = pk2(p[8*hh+0], p[8*hh+1]), w1 = pk2(p[8*hh+2], p[8*hh+3]);
                const u32 w2 = pk2(p[8*hh+4], p[8*hh+5]), w3 = pk2(p[8*hh+6], p[8*hh+7]);
                const int srcA = ((g & 1) * 2) * 16 + l15, srcB = srcA + 16;
                const u32 a0 = (u32)__shfl((int)w0, srcA, 64), a1 = (u32)__shfl((int)w1, srcA, 64);
                const u32 a2 = (u32)__shfl((int)w2, srcA, 64), a3 = (u32)__shfl((int)w3, srcA, 64);
                const u32 b0 = (u32)__shfl((int)w0, srcB, 64), b1 = (u32)__shfl((int)w1, srcB, 64);
                const u32 b2 = (u32)__shfl((int)w2, srcB, 64), b3 = (u32)__shfl((int)w3, srcB, 64);
                const bool losel = (g < 2);
                const u32 d0 = losel ? a0 : a2, d1 = losel ? a1 : a3;
                const u32 d2 = losel ? b0 : b2, d3 = losel ? b1 : b3;
                s16x8 pa;
                pa[0] = (short)(d0 & 0xffff); pa[1] = (short)(d0 >> 16);
                pa[2] = (short)(d1 & 0xffff); pa[3] = (short)(d1 >> 16);
                pa[4] = (short)(d2 & 0xffff); pa[5] = (short)(d2 >> 16);
                pa[6] = (short)(d3 & 0xffff); pa[7] = (short)(d3 >> 16);
                const int so = ((hh * 4 + g) ^ h7) << 4;
#pragma unroll
                for (int cc = 0; cc < 4; ++cc) {
                    const s16x8 va = *(const s16x8*)(Vb + (cc * 16 + l15) * 128 + so);
                    o[cc] = __builtin_amdgcn_mfma_f32_16x16x32_bf16(va, pa, o[cc], 0, 0, 0);
                }
            }
#endif
        }
        __syncthreads();
    }
#undef STAGE

    if (active) {
        if (mode) {
            const long slot = ((long)batch * 256 + qt) * MAXC + c;
            float* pb = partO + (slot * 16 + l15) * 64;
#pragma unroll
            for (int cc = 0; cc < 4; ++cc) {
                float4 stv; stv.x = o[cc][0]; stv.y = o[cc][1];
                stv.z = o[cc][2]; stv.w = o[cc][3];
                *(float4*)(pb + cc * 16 + 4 * g) = stv;
            }
            if (lane < 16) {
                float2 s2; s2.x = m; s2.y = lacc;
                *(float2*)(stats2 + (slot * 16 + l15) * 2) = s2;
            }
        } else {
            const float inv = 1.0f / lacc;
            float* ob = out + base + (long)(qw + l15) * H_DIM;
#pragma unroll
            for (int cc = 0; cc < 4; ++cc) {
                float4 stv; stv.x = o[cc][0] * inv; stv.y = o[cc][1] * inv;
                stv.z = o[cc][2] * inv; stv.w = o[cc][3] * inv;
                *(float4*)(ob + cc * 16 + 4 * g) = stv;
            }
        }
    }
}

// ---------------------------------------------------------------------------
// Kernel 3: split-K combine (exp2 domain). Unchanged.
// ---------------------------------------------------------------------------
__global__ __launch_bounds__(256) void combine_kernel(
    const float* __restrict__ partO, const float* __restrict__ stats2,
    float* __restrict__ out)
{
    const int wv   = threadIdx.x >> 6;
    const int lane = threadIdx.x & 63;
    const int l15 = lane & 15, g = lane >> 4;
    const int bid = blockIdx.x;
    const int batch = bid & 3;
    const int qt = (bid >> 2) * 4 + wv;
    const int nc = (qt * 16) / CHUNK + 1;

    f32x4 O[4];
    f32x4 zz = {0.f, 0.f, 0.f, 0.f};
#pragma unroll
    for (int i = 0; i < 4; ++i) O[i] = zz;
    float M = -INFINITY, L = 0.f;

    for (int c = 0; c < nc; ++c) {
        const long slot = ((long)batch * 256 + qt) * MAXC + c;
        const float2 s = *(const float2*)(stats2 + (slot * 16 + l15) * 2);
        const float Mn = fmaxf(M, s.x);
        const float a  = exp2f(M - Mn);
        const float bw = exp2f(s.x - Mn);
        const float* pb = partO + (slot * 16 + l15) * 64 + g * 16;
#pragma unroll
        for (int i = 0; i < 4; ++i) {
            const f32x4 oc = *(const f32x4*)(pb + 4 * i);
            O[i] = O[i] * a + oc * bw;
        }
        L = L * a + s.y * bw;
        M = Mn;
    }

    const float inv = 1.0f / L;
    float* ob = out + ((long)batch * S_LEN + qt * 16 + l15) * H_DIM + g * 16;
#pragma unroll
    for (int i = 0; i < 4; ++i) {
        float4 st; st.x = O[i][0] * inv; st.y = O[i][1] * inv;
        st.z = O[i][2] * inv; st.w = O[i][3] * inv;
        *(float4*)(ob + 4 * i) = st;
    }
}

// ---------------------------------------------------------------------------
extern "C" void kernel_launch(void* const* d_in, const int* in_sizes, int n_in,
                              void* d_out, int out_size, void* d_ws, size_t ws_size,
                              hipStream_t stream)
{
    const float* x  = (const float*)d_in[0];
    const float* Wq = (const float*)d_in[1];
    const float* bq = (const float*)d_in[2];
    const float* Wk = (const float*)d_in[3];
    const float* bk = (const float*)d_in[4];
    const float* Wv = (const float*)d_in[5];
    const float* bv = (const float*)d_in[6];
    float* out = (float*)d_out;

    const long BSH = (long)B_SZ * S_LEN * H_DIM;   // 1,048,576
    u16* qs = (u16*)d_ws;
    u16* ks = qs + BSH;
    u16* vt = ks + BSH;
    u16* wt = vt + BSH;                            // 192*1024 u16 (frag-ordered)

    const size_t PART_OFF = (size_t)8 << 20;
    const size_t slots = (size_t)1024 * MAXC;
    const int split_ok = (PART_OFF + slots * 4224 <= ws_size);
    float* partO  = (float*)((char*)d_ws + PART_OFF);
    float* stats2 = partO + slots * 1024;

    wt_kernel<<<768, 256, 0, stream>>>(Wq, Wk, Wv, wt);
    proj_kernel<<<B_SZ * S_LEN / 64, 256, 0, stream>>>(x, wt, bq, bk, bv, qs, ks, vt);
    if (split_ok) {
        attn_stage_kernel<<<1152, 256, 0, stream>>>(qs, ks, vt, out, partO, stats2, 1);
        combine_kernel<<<256, 256, 0, stream>>>(partO, stats2, out);
    } else {
        attn_stage_kernel<<<256, 256, 0, stream>>>(qs, ks, vt, out, partO, stats2, 0);
    }
}

// Round 8
// 72.104 us; speedup vs baseline: 3.6476x; 1.0893x over previous
//
#include <hip/hip_runtime.h>
#include <math.h>

#define E_DIM 1024
#define H_DIM 64
#define S_LEN 4096
#define B_SZ  4

typedef short s16x8 __attribute__((ext_vector_type(8)));
typedef short s16x4 __attribute__((ext_vector_type(4)));
typedef float f32x4 __attribute__((ext_vector_type(4)));
typedef unsigned short u16;
typedef unsigned int u32;

// q is pre-scaled by 1/sqrt(H) * log2(e) so attention uses exp2 throughout.
#define QSCALE 0.180336880f
#define CHUNK  512
#define MAXC   8      // S_LEN / CHUNK
#define KB     64     // keys per staged LDS tile (attention)

static __device__ __forceinline__ u16 f2b(float f) {
    u32 u = __builtin_bit_cast(u32, f);
    u += 0x7fffu + ((u >> 16) & 1u);        // RNE
    return (u16)(u >> 16);
}
static __device__ __forceinline__ u32 pk2(float lo, float hi) {
    return (u32)f2b(lo) | ((u32)f2b(hi) << 16);
}

// async global->LDS, 16B per lane; LDS dest = wave-uniform base + lane*16,
// global source is per-lane.
static __device__ __forceinline__ void gload16(const void* g, void* l) {
    __builtin_amdgcn_global_load_lds(
        (const __attribute__((address_space(1))) u32*)g,
        (__attribute__((address_space(3))) u32*)l, 16, 0, 0);
}

#if defined(__has_builtin)
#  if __has_builtin(__builtin_amdgcn_mfma_f32_16x16x16bf16_1k)
#    define USE_1K 1
#  else
#    define USE_1K 0
#  endif
#else
#  define USE_1K 0
#endif

// ---------------------------------------------------------------------------
// Kernel 0: W -> bf16, FRAG-ORDERED layout (unchanged, verified round 6/7).
// wt[mh*16384 + kestep*512 + lane*8 + j], lane = (g<<4)|l15,
// row h = mh*16+l15, e = kestep*32 + g*8 + j.
// ---------------------------------------------------------------------------
__global__ __launch_bounds__(256) void wt_kernel(
    const float* __restrict__ Wq, const float* __restrict__ Wk,
    const float* __restrict__ Wv, u16* __restrict__ wt)
{
    const int flat = blockIdx.x * 256 + threadIdx.x;   // 0..196607
    const int mat = flat >> 16;
    const int within = flat & 65535;                   // = k*64 + h
    const int kk = within >> 6;
    const int h  = within & 63;
    const float* W = (mat == 0) ? Wq : (mat == 1) ? Wk : Wv;
    const int mh = mat * 4 + (h >> 4);
    const int lane = (((kk >> 3) & 3) << 4) | (h & 15);
    const long idx = (long)mh * 16384 + (long)(kk >> 5) * 512 + lane * 8 + (kk & 7);
    wt[idx] = f2b(W[within]);
}

// ---------------------------------------------------------------------------
// Kernel 1: QKV projection — canonical LDS-staged MFMA GEMM.
// 256 blocks x 4 waves x 16 rows = 64 rows/block; 16 E-chunks of 64.
// Per chunk both operands staged: x-tile 16KB (XOR-16 swizzled via pre-
// swizzled global source) + wt-slice 24KB (frag-ordered, linear). Double
// buffered (80KB LDS). Exactly 10 DMA ops/wave/stage -> counted vmcnt(10)
// with raw s_barrier (never drain to 0 in the loop). Compute phase has ZERO
// vm ops: wt frag reads are contiguous ds_read_b128; x reads 4-way floor.
// Outputs: q bf16 row-major PRE-SCALED by QSCALE; k row-major; v transposed
// Vt[b][h][s] bf16.
// ---------------------------------------------------------------------------
__global__ __launch_bounds__(256) void proj_kernel(
    const float* __restrict__ x, const u16* __restrict__ wt,
    const float* __restrict__ bq, const float* __restrict__ bk,
    const float* __restrict__ bv,
    u16* __restrict__ qs, u16* __restrict__ ks, u16* __restrict__ vt)
{
    __shared__ __align__(1024) char smem[81920];  // x: 2x16KB, wt: 2x24KB

    const int tid  = threadIdx.x;
    const int w    = tid >> 6;
    const int lane = tid & 63;
    const int l15 = lane & 15, g = lane >> 4;
    const long row0 = (long)blockIdx.x * 64;
    const char* xgb = (const char*)(x + row0 * E_DIM);
    const char* wgb = (const char*)wt;

    f32x4 zz = {0.f, 0.f, 0.f, 0.f};
    f32x4 o[12];
#pragma unroll
    for (int i = 0; i < 12; ++i) o[i] = zz;

#define XOFF(b) ((b) * 16384)
#define WOFF(b) (32768 + (b) * 24576)

// stage chunk c into buffer b: 4 x-loads + 6 wt-loads per wave (10 vm ops).
// x LDS: phys[row][p] = x[row][p ^ (row&15)] (16B slots within 256B row).
#define PSTAGE(b, c) do {                                                     \
    _Pragma("unroll")                                                         \
    for (int ii = 0; ii < 4; ++ii) {                                          \
        const int i = w * 4 + ii;                                             \
        const int row = i * 4 + (lane >> 4);                                  \
        const int sslot = (lane & 15) ^ (row & 15);                           \
        gload16(xgb + (long)row * 4096 + (c) * 256 + (sslot << 4),            \
                smem + XOFF(b) + i * 1024);                                   \
    }                                                                         \
    _Pragma("unroll")                                                         \
    for (int j = 0; j < 6; ++j) {                                             \
        const int f = w * 6 + j;                                              \
        const int mh = f >> 1, ksl = f & 1;                                   \
        gload16(wgb + (long)mh * 32768 + ((c) * 2 + ksl) * 1024 + lane * 16,  \
                smem + WOFF(b) + f * 1024);                                   \
    }                                                                         \
} while (0)

#define PCOMP(b) do {                                                         \
    _Pragma("unroll")                                                         \
    for (int ksl = 0; ksl < 2; ++ksl) {                                       \
        const char* xrow = smem + XOFF(b) + (w * 16 + l15) * 256;             \
        const float4 fa = *(const float4*)(                                   \
            xrow + (((ksl * 8 + 2 * g) ^ l15) << 4));                         \
        const float4 fb = *(const float4*)(                                   \
            xrow + (((ksl * 8 + 2 * g + 1) ^ l15) << 4));                     \
        s16x8 xa;                                                             \
        xa[0] = (short)f2b(fa.x); xa[1] = (short)f2b(fa.y);                   \
        xa[2] = (short)f2b(fa.z); xa[3] = (short)f2b(fa.w);                   \
        xa[4] = (short)f2b(fb.x); xa[5] = (short)f2b(fb.y);                   \
        xa[6] = (short)f2b(fb.z); xa[7] = (short)f2b(fb.w);                   \
        _Pragma("unroll")                                                     \
        for (int mh = 0; mh < 12; ++mh) {                                     \
            const s16x8 wa = *(const s16x8*)(                                 \
                smem + WOFF(b) + (mh * 2 + ksl) * 1024 + lane * 16);          \
            o[mh] = __builtin_amdgcn_mfma_f32_16x16x32_bf16(wa, xa, o[mh],    \
                                                            0, 0, 0);         \
        }                                                                     \
    }                                                                         \
} while (0)

#define WAITV10() do { asm volatile("s_waitcnt vmcnt(10)" ::: "memory");      \
    __builtin_amdgcn_sched_barrier(0); } while (0)
#define WAITV0() do { asm volatile("s_waitcnt vmcnt(0)" ::: "memory");        \
    __builtin_amdgcn_sched_barrier(0); } while (0)
#define LGKM0() do { asm volatile("s_waitcnt lgkmcnt(0)" ::: "memory");       \
    __builtin_amdgcn_sched_barrier(0); } while (0)
#define BAR() do { __builtin_amdgcn_s_barrier();                              \
    __builtin_amdgcn_sched_barrier(0); } while (0)

    PSTAGE(0, 0);
    PSTAGE(1, 1);
#pragma unroll
    for (int c = 0; c < 16; ++c) {
        const int b = c & 1;
        if (c == 15) { WAITV0(); } else { WAITV10(); }
        BAR();                      // stage(c) visible to all waves
        PCOMP(b);
        if (c + 2 < 16) {
            LGKM0();                // this wave's reads of buf b complete
            BAR();                  // all waves done reading buf b
            PSTAGE(b, c + 2);
        }
    }
#undef PSTAGE
#undef PCOMP
#undef WAITV10
#undef WAITV0
#undef LGKM0
#undef BAR
#undef XOFF
#undef WOFF

    const long rg = row0 + w * 16 + l15;   // this lane's x-row (D column)
    const int batch = (int)(rg >> 12);
    const int sl = (int)(rg & 4095);
#pragma unroll
    for (int mh = 0; mh < 12; ++mh) {
        const int mat = mh >> 2, hb = mh & 3;
        const float* bias = (mat == 0) ? bq : (mat == 1) ? bk : bv;
        const float4 bb = *(const float4*)(bias + hb * 16 + 4 * g);
        float r0 = o[mh][0] + bb.x, r1 = o[mh][1] + bb.y;
        float r2 = o[mh][2] + bb.z, r3 = o[mh][3] + bb.w;
        if (mat == 0) {
            r0 *= QSCALE; r1 *= QSCALE; r2 *= QSCALE; r3 *= QSCALE;
            uint2 pk; pk.x = pk2(r0, r1); pk.y = pk2(r2, r3);
            *(uint2*)(qs + rg * H_DIM + hb * 16 + 4 * g) = pk;
        } else if (mat == 1) {
            uint2 pk; pk.x = pk2(r0, r1); pk.y = pk2(r2, r3);
            *(uint2*)(ks + rg * H_DIM + hb * 16 + 4 * g) = pk;
        } else {
            const long hbase = (long)batch * H_DIM + hb * 16 + 4 * g;
            vt[(hbase + 0) * S_LEN + sl] = f2b(r0);
            vt[(hbase + 1) * S_LEN + sl] = f2b(r1);
            vt[(hbase + 2) * S_LEN + sl] = f2b(r2);
            vt[(hbase + 3) * S_LEN + sl] = f2b(r3);
        }
    }
}

// ---------------------------------------------------------------------------
// Kernel 2: LDS-staged split-K causal flash attention (unchanged, round 6/7).
// ---------------------------------------------------------------------------
__global__ __launch_bounds__(256) void attn_stage_kernel(
    const u16* __restrict__ q, const u16* __restrict__ k,
    const u16* __restrict__ vt, float* __restrict__ out,
    float* __restrict__ partO, float* __restrict__ stats2, int mode)
{
    __shared__ __align__(1024) char smem[32768];   // 2 bufs x (8KB K + 8KB V)

    const int tid  = threadIdx.x;
    const int w    = tid >> 6;
    const int lane = tid & 63;
    const int l15 = lane & 15, g = lane >> 4;
    const int h7  = l15 & 7;
    const int bid = blockIdx.x;
    const int batch = bid & 3;
    const int r = bid >> 2;

    int qg, c;
    if (mode) {                          // prefix-decode r -> (qg, c)
        if      (r < 8)   { qg = r;                  c = 0;      }
        else if (r < 24)  { int rr = r - 8;   qg = 8  + rr / 2; c = rr % 2; }
        else if (r < 48)  { int rr = r - 24;  qg = 16 + rr / 3; c = rr % 3; }
        else if (r < 80)  { int rr = r - 48;  qg = 24 + rr / 4; c = rr % 4; }
        else if (r < 120) { int rr = r - 80;  qg = 32 + rr / 5; c = rr % 5; }
        else if (r < 168) { int rr = r - 120; qg = 40 + rr / 6; c = rr % 6; }
        else if (r < 224) { int rr = r - 168; qg = 48 + rr / 7; c = rr % 7; }
        else              { int rr = r - 224; qg = 56 + rr / 8; c = rr % 8; }
    } else { qg = r; c = 0; }

    const int chunk_sz = mode ? CHUNK : S_LEN;
    const int qt = 4 * qg + w;
    const int qw = qt * 16;
    const int k0 = c * CHUNK;
    const int kend = min(k0 + chunk_sz, qg * 64 + 64);
    const int T = (kend - k0 + KB - 1) >> 6;
    const bool active = (k0 <= qw + 15);

    const long base = (long)batch * S_LEN * H_DIM;
    const char* kg = (const char*)(k + base);
    const char* vg = (const char*)(vt + (long)batch * H_DIM * S_LEN);

    const u16* qrow = q + base + (long)(qw + l15) * H_DIM;
    const s16x8 qa0 = *(const s16x8*)(qrow + g * 8);
    const s16x8 qa1 = *(const s16x8*)(qrow + 32 + g * 8);

    f32x4 o[4];
    f32x4 zz = {0.f, 0.f, 0.f, 0.f};
#pragma unroll
    for (int cc = 0; cc < 4; ++cc) o[cc] = zz;
    float m = -INFINITY, lacc = 0.f;
    const int qglane = qw + l15;

    const int srow  = lane >> 3;
    const int sslot = (lane & 7) ^ srow;

#define STAGE(bufb, kv0_) do {                                               \
    char* kd = smem + (bufb) + 2048 * w;                                     \
    const long krw = (long)((kv0_) + 16 * w + srow);                         \
    gload16(kg + krw * 128 + (sslot << 4), kd);                              \
    gload16(kg + (krw + 8) * 128 + (sslot << 4), kd + 1024);                 \
    char* vd = smem + (bufb) + 8192 + 2048 * w;                              \
    const long vrw = (long)(16 * w + srow);                                  \
    const long vco = (long)(kv0_) * 2 + (sslot << 4);                        \
    gload16(vg + vrw * 8192 + vco, vd);                                      \
    gload16(vg + (vrw + 8) * 8192 + vco, vd + 1024);                         \
} while (0)

    STAGE(0, k0);
    __syncthreads();

    for (int t = 0; t < T; ++t) {
        const int cb  = (t & 1) << 14;
        const int kv0 = k0 + t * KB;
        if (t + 1 < T) STAGE(cb ^ 16384, kv0 + KB);

        if (active && kv0 <= qw + 15) {
            const char* Kb = smem + cb;
            const char* Vb = smem + cb + 8192;
            f32x4 st[4];
#pragma unroll
            for (int kt = 0; kt < 4; ++kt) {
                const int rb = (kt * 16 + l15) * 128;
                const s16x8 ka0 = *(const s16x8*)(Kb + rb + ((g ^ h7) << 4));
                const s16x8 ka1 = *(const s16x8*)(Kb + rb + (((4 + g) ^ h7) << 4));
                st[kt] = __builtin_amdgcn_mfma_f32_16x16x32_bf16(ka0, qa0, zz, 0, 0, 0);
                st[kt] = __builtin_amdgcn_mfma_f32_16x16x32_bf16(ka1, qa1, st[kt], 0, 0, 0);
            }
            float p[16];
            if (kv0 + KB - 1 > qw) {
#pragma unroll
                for (int kt = 0; kt < 4; ++kt)
#pragma unroll
                    for (int rr2 = 0; rr2 < 4; ++rr2)
                        p[kt * 4 + rr2] =
                            (kv0 + kt * 16 + 4 * g + rr2 <= qglane) ? st[kt][rr2] : -INFINITY;
            } else {
#pragma unroll
                for (int i = 0; i < 16; ++i) p[i] = st[i >> 2][i & 3];
            }
            float pm = p[0];
#pragma unroll
            for (int i = 1; i < 16; ++i) pm = fmaxf(pm, p[i]);
            pm = fmaxf(pm, __shfl_xor(pm, 16, 64));
            pm = fmaxf(pm, __shfl_xor(pm, 32, 64));
            const float mnew = fmaxf(m, pm);
            const float corr = exp2f(m - mnew);
            float psum = 0.f;
#pragma unroll
            for (int i = 0; i < 16; ++i) { p[i] = exp2f(p[i] - mnew); psum += p[i]; }
            psum += __shfl_xor(psum, 16, 64);
            psum += __shfl_xor(psum, 32, 64);
            lacc = lacc * corr + psum;
            m = mnew;
#pragma unroll
            for (int cc = 0; cc < 4; ++cc) {
                o[cc][0] *= corr; o[cc][1] *= corr; o[cc][2] *= corr; o[cc][3] *= corr;
            }
#if USE_1K
#pragma unroll
            for (int kt = 0; kt < 4; ++kt) {
                s16x4 pa;
                pa[0] = (short)f2b(p[kt * 4 + 0]); pa[1] = (short)f2b(p[kt * 4 + 1]);
                pa[2] = (short)f2b(p[kt * 4 + 2]); pa[3] = (short)f2b(p[kt * 4 + 3]);
                const int so = (((kt * 2 + (g >> 1)) ^ h7) << 4) + (g & 1) * 8;
#pragma unroll
                for (int cc = 0; cc < 4; ++cc) {
                    const s16x4 va = *(const s16x4*)(Vb + (cc * 16 + l15) * 128 + so);
                    o[cc] = __builtin_amdgcn_mfma_f32_16x16x16bf16_1k(va, pa, o[cc], 0, 0, 0);
                }
            }
#else
#pragma unroll
            for (int hh = 0; hh < 2; ++hh) {
                const u32 w0 = pk2(p[8*hh+0], p[8*hh+1]), w1 = pk2(p[8*hh+2], p[8*hh+3]);
                const u32 w2 = pk2(p[8*hh+4], p[8*hh+5]), w3 = pk2(p[8*hh+6], p[8*hh+7]);
                const int srcA = ((g & 1) * 2) * 16 + l15, srcB = srcA + 16;
                const u32 a0 = (u32)__shfl((int)w0, srcA, 64), a1 = (u32)__shfl((int)w1, srcA, 64);
                const u32 a2 = (u32)__shfl((int)w2, srcA, 64), a3 = (u32)__shfl((int)w3, srcA, 64);
                const u32 b0 = (u32)__shfl((int)w0, srcB, 64), b1 = (u32)__shfl((int)w1, srcB, 64);
                const u32 b2 = (u32)__shfl((int)w2, srcB, 64), b3 = (u32)__shfl((int)w3, srcB, 64);
                const bool losel = (g < 2);
                const u32 d0 = losel ? a0 : a2, d1 = losel ? a1 : a3;
                const u32 d2 = losel ? b0 : b2, d3 = losel ? b1 : b3;
                s16x8 pa;
                pa[0] = (short)(d0 & 0xffff); pa[1] = (short)(d0 >> 16);
                pa[2] = (short)(d1 & 0xffff); pa[3] = (short)(d1 >> 16);
                pa[4] = (short)(d2 & 0xffff); pa[5] = (short)(d2 >> 16);
                pa[6] = (short)(d3 & 0xffff); pa[7] = (short)(d3 >> 16);
                const int so = ((hh * 4 + g) ^ h7) << 4;
#pragma unroll
                for (int cc = 0; cc < 4; ++cc) {
                    const s16x8 va = *(const s16x8*)(Vb + (cc * 16 + l15) * 128 + so);
                    o[cc] = __builtin_amdgcn_mfma_f32_16x16x32_bf16(va, pa, o[cc], 0, 0, 0);
                }
            }
#endif
        }
        __syncthreads();
    }
#undef STAGE

    if (active) {
        if (mode) {
            const long slot = ((long)batch * 256 + qt) * MAXC + c;
            float* pb = partO + (slot * 16 + l15) * 64;
#pragma unroll
            for (int cc = 0; cc < 4; ++cc) {
                float4 stv; stv.x = o[cc][0]; stv.y = o[cc][1];
                stv.z = o[cc][2]; stv.w = o[cc][3];
                *(float4*)(pb + cc * 16 + 4 * g) = stv;
            }
            if (lane < 16) {
                float2 s2; s2.x = m; s2.y = lacc;
                *(float2*)(stats2 + (slot * 16 + l15) * 2) = s2;
            }
        } else {
            const float inv = 1.0f / lacc;
            float* ob = out + base + (long)(qw + l15) * H_DIM;
#pragma unroll
            for (int cc = 0; cc < 4; ++cc) {
                float4 stv; stv.x = o[cc][0] * inv; stv.y = o[cc][1] * inv;
                stv.z = o[cc][2] * inv; stv.w = o[cc][3] * inv;
                *(float4*)(ob + cc * 16 + 4 * g) = stv;
            }
        }
    }
}

// ---------------------------------------------------------------------------
// Kernel 3: split-K combine (exp2 domain). Unchanged.
// ---------------------------------------------------------------------------
__global__ __launch_bounds__(256) void combine_kernel(
    const float* __restrict__ partO, const float* __restrict__ stats2,
    float* __restrict__ out)
{
    const int wv   = threadIdx.x >> 6;
    const int lane = threadIdx.x & 63;
    const int l15 = lane & 15, g = lane >> 4;
    const int bid = blockIdx.x;
    const int batch = bid & 3;
    const int qt = (bid >> 2) * 4 + wv;
    const int nc = (qt * 16) / CHUNK + 1;

    f32x4 O[4];
    f32x4 zz = {0.f, 0.f, 0.f, 0.f};
#pragma unroll
    for (int i = 0; i < 4; ++i) O[i] = zz;
    float M = -INFINITY, L = 0.f;

    for (int c = 0; c < nc; ++c) {
        const long slot = ((long)batch * 256 + qt) * MAXC + c;
        const float2 s = *(const float2*)(stats2 + (slot * 16 + l15) * 2);
        const float Mn = fmaxf(M, s.x);
        const float a  = exp2f(M - Mn);
        const float bw = exp2f(s.x - Mn);
        const float* pb = partO + (slot * 16 + l15) * 64 + g * 16;
#pragma unroll
        for (int i = 0; i < 4; ++i) {
            const f32x4 oc = *(const f32x4*)(pb + 4 * i);
            O[i] = O[i] * a + oc * bw;
        }
        L = L * a + s.y * bw;
        M = Mn;
    }

    const float inv = 1.0f / L;
    float* ob = out + ((long)batch * S_LEN + qt * 16 + l15) * H_DIM + g * 16;
#pragma unroll
    for (int i = 0; i < 4; ++i) {
        float4 st; st.x = O[i][0] * inv; st.y = O[i][1] * inv;
        st.z = O[i][2] * inv; st.w = O[i][3] * inv;
        *(float4*)(ob + 4 * i) = st;
    }
}

// ---------------------------------------------------------------------------
extern "C" void kernel_launch(void* const* d_in, const int* in_sizes, int n_in,
                              void* d_out, int out_size, void* d_ws, size_t ws_size,
                              hipStream_t stream)
{
    const float* x  = (const float*)d_in[0];
    const float* Wq = (const float*)d_in[1];
    const float* bq = (const float*)d_in[2];
    const float* Wk = (const float*)d_in[3];
    const float* bk = (const float*)d_in[4];
    const float* Wv = (const float*)d_in[5];
    const float* bv = (const float*)d_in[6];
    float* out = (float*)d_out;

    const long BSH = (long)B_SZ * S_LEN * H_DIM;   // 1,048,576
    u16* qs = (u16*)d_ws;
    u16* ks = qs + BSH;
    u16* vt = ks + BSH;
    u16* wt = vt + BSH;                            // 192*1024 u16 (frag-ordered)

    const size_t PART_OFF = (size_t)8 << 20;
    const size_t slots = (size_t)1024 * MAXC;
    const int split_ok = (PART_OFF + slots * 4224 <= ws_size);
    float* partO  = (float*)((char*)d_ws + PART_OFF);
    float* stats2 = partO + slots * 1024;

    wt_kernel<<<768, 256, 0, stream>>>(Wq, Wk, Wv, wt);
    proj_kernel<<<B_SZ * S_LEN / 64, 256, 0, stream>>>(x, wt, bq, bk, bv, qs, ks, vt);
    if (split_ok) {
        attn_stage_kernel<<<1152, 256, 0, stream>>>(qs, ks, vt, out, partO, stats2, 1);
        combine_kernel<<<256, 256, 0, stream>>>(partO, stats2, out);
    } else {
        attn_stage_kernel<<<256, 256, 0, stream>>>(qs, ks, vt, out, partO, stats2, 0);
    }
}